// Round 1
// baseline (1020.436 us; speedup 1.0000x reference)
//
#include <hip/hip_runtime.h>
#include <cstddef>

// ---------------------------------------------------------------------------
// GraphFiLM: 2x FiLMConv(mean agg) + leaky_relu + linear head, fp32 baseline.
// N = 100000 nodes, D = 64 features, E = 1.6M edges.
// ---------------------------------------------------------------------------

#define THREADS 256

__device__ __forceinline__ void stage_w(float (*WT)[64], const float* __restrict__ W,
                                        int ld, int off, int t) {
  // stage 64x64 col-slice of W (row-major, leading dim ld, col offset off)
  for (int q = t; q < 1024; q += THREADS) {
    int k = q >> 4;
    int c4 = q & 15;
    *(float4*)&WT[k][c4 * 4] = *(const float4*)(W + (size_t)k * ld + off + c4 * 4);
  }
}

__device__ __forceinline__ void gemm_pass(const float (*XT)[64], const float (*WT)[64],
                                          int m0, int c0, float acc[4][4]) {
#pragma unroll 4
  for (int k = 0; k < 64; ++k) {
    float4 xv = *(const float4*)&XT[k][m0];
    float4 wv = *(const float4*)&WT[k][c0];
    float xs[4] = {xv.x, xv.y, xv.z, xv.w};
    float ws[4] = {wv.x, wv.y, wv.z, wv.w};
#pragma unroll
    for (int i = 0; i < 4; ++i)
#pragma unroll
      for (int j = 0; j < 4; ++j)
        acc[i][j] = fmaf(xs[i], ws[j], acc[i][j]);
  }
}

// MODE 0: O0 = X@W0 (lin); O1 = X@W1 + bias[0:64] (beta); O2 = X@W2 + bias[64:128] (gamma)
// MODE 1: O0 = relu( (X@W2) * (X@W0) + (X@W1) )   [gamma_s * skip + beta_s]
template <int MODE>
__global__ __launch_bounds__(THREADS) void gemm_node(
    const float* __restrict__ X, int N,
    const float* __restrict__ W0, int ld0, int off0,
    const float* __restrict__ W1, int ld1, int off1,
    const float* __restrict__ W2, int ld2, int off2,
    const float* __restrict__ bias,
    float* __restrict__ O0, float* __restrict__ O1, float* __restrict__ O2) {
  __shared__ float XT[64][64];  // XT[k][m]  (transposed X tile)
  __shared__ float WT[64][64];  // WT[k][c]
  int t = threadIdx.x;
  int row0 = blockIdx.x * 64;

  // stage X tile (transposed into LDS)
  for (int q = t; q < 1024; q += THREADS) {
    int m = q >> 4;
    int k4 = q & 15;
    int gr = row0 + m;
    float4 v = make_float4(0.f, 0.f, 0.f, 0.f);
    if (gr < N) v = *(const float4*)(X + (size_t)gr * 64 + k4 * 4);
    XT[k4 * 4 + 0][m] = v.x;
    XT[k4 * 4 + 1][m] = v.y;
    XT[k4 * 4 + 2][m] = v.z;
    XT[k4 * 4 + 3][m] = v.w;
  }

  int m0 = (t & 15) * 4;
  int c0 = (t >> 4) * 4;

  float a0[4][4], a1[4][4], a2[4][4];
#pragma unroll
  for (int i = 0; i < 4; ++i)
#pragma unroll
    for (int j = 0; j < 4; ++j) {
      a0[i][j] = 0.f;
      a1[i][j] = 0.f;
      a2[i][j] = 0.f;
    }

  stage_w(WT, W0, ld0, off0, t);
  __syncthreads();
  gemm_pass(XT, WT, m0, c0, a0);
  __syncthreads();
  stage_w(WT, W1, ld1, off1, t);
  __syncthreads();
  gemm_pass(XT, WT, m0, c0, a1);
  __syncthreads();
  stage_w(WT, W2, ld2, off2, t);
  __syncthreads();
  gemm_pass(XT, WT, m0, c0, a2);

  // epilogue
#pragma unroll
  for (int i = 0; i < 4; ++i) {
    int gr = row0 + m0 + i;
    if (gr >= N) continue;
    if (MODE == 0) {
      float4 h = {a0[i][0], a0[i][1], a0[i][2], a0[i][3]};
      float4 be = {a1[i][0] + bias[c0 + 0], a1[i][1] + bias[c0 + 1],
                   a1[i][2] + bias[c0 + 2], a1[i][3] + bias[c0 + 3]};
      float4 ga = {a2[i][0] + bias[64 + c0 + 0], a2[i][1] + bias[64 + c0 + 1],
                   a2[i][2] + bias[64 + c0 + 2], a2[i][3] + bias[64 + c0 + 3]};
      *(float4*)(O0 + (size_t)gr * 64 + c0) = h;
      *(float4*)(O1 + (size_t)gr * 64 + c0) = be;
      *(float4*)(O2 + (size_t)gr * 64 + c0) = ga;
    } else {
      float4 s;
      s.x = fmaxf(fmaf(a2[i][0], a0[i][0], a1[i][0]), 0.f);
      s.y = fmaxf(fmaf(a2[i][1], a0[i][1], a1[i][1]), 0.f);
      s.z = fmaxf(fmaf(a2[i][2], a0[i][2], a1[i][2]), 0.f);
      s.w = fmaxf(fmaf(a2[i][3], a0[i][3], a1[i][3]), 0.f);
      *(float4*)(O0 + (size_t)gr * 64 + c0) = s;
    }
  }
}

// degree: one thread per edge
__global__ __launch_bounds__(THREADS) void deg_kernel(const int* __restrict__ dst,
                                                      float* __restrict__ deg, int E) {
  int e = blockIdx.x * THREADS + threadIdx.x;
  if (e < E) atomicAdd(&deg[dst[e]], 1.0f);
}

// edge phase: one wave (64 lanes) per edge, lane = feature index
__global__ __launch_bounds__(THREADS) void edge_kernel(
    const float* __restrict__ H, const float* __restrict__ GAMMA,
    const float* __restrict__ BETA, float* __restrict__ AGG,
    const int* __restrict__ src, const int* __restrict__ dst, int E) {
  long long tid = (long long)blockIdx.x * THREADS + threadIdx.x;
  int e = (int)(tid >> 6);
  int j = (int)(tid & 63);
  if (e >= E) return;
  int s = src[e];
  int d = dst[e];
  size_t doff = (size_t)d * 64 + j;
  float g = GAMMA[doff];
  float b = BETA[doff];
  float h = H[(size_t)s * 64 + j];
  float m = fmaxf(fmaf(g, h, b), 0.f);
  atomicAdd(&AGG[doff], m);
}

// finalize: Xn = leaky_relu(S + AGG / max(deg,1)), float4-vectorized
__global__ __launch_bounds__(THREADS) void finalize_kernel(
    const float* __restrict__ S, const float* __restrict__ AGG,
    const float* __restrict__ deg, float* __restrict__ Xn, int N) {
  size_t i = (size_t)blockIdx.x * THREADS + threadIdx.x;  // float4 index
  if (i >= (size_t)N * 16) return;
  int n = (int)(i >> 4);
  float inv = 1.f / fmaxf(deg[n], 1.f);
  float4 s = ((const float4*)S)[i];
  float4 a = ((const float4*)AGG)[i];
  float4 o;
  o.x = fmaf(a.x, inv, s.x);
  o.y = fmaf(a.y, inv, s.y);
  o.z = fmaf(a.z, inv, s.z);
  o.w = fmaf(a.w, inv, s.w);
  o.x = o.x > 0.f ? o.x : 0.01f * o.x;
  o.y = o.y > 0.f ? o.y : 0.01f * o.y;
  o.z = o.z > 0.f ? o.z : 0.01f * o.z;
  o.w = o.w > 0.f ? o.w : 0.01f * o.w;
  ((float4*)Xn)[i] = o;
}

// head: one wave per node, shuffle reduce over 64 features
__global__ __launch_bounds__(THREADS) void head_kernel(
    const float* __restrict__ X, const float* __restrict__ Wout,
    const float* __restrict__ bout, float* __restrict__ out, int N) {
  int t = threadIdx.x;
  int node = blockIdx.x * 4 + (t >> 6);
  int lane = t & 63;
  if (node >= N) return;
  float v = X[(size_t)node * 64 + lane] * Wout[lane];
#pragma unroll
  for (int off = 32; off; off >>= 1) v += __shfl_xor(v, off, 64);
  if (lane == 0) out[node] = v + bout[0];
}

extern "C" void kernel_launch(void* const* d_in, const int* in_sizes, int n_in,
                              void* d_out, int out_size, void* d_ws, size_t ws_size,
                              hipStream_t stream) {
  const float* x = (const float*)d_in[0];
  const int* ei = (const int*)d_in[1];
  const float* Wlin1 = (const float*)d_in[2];
  const float* Wfilm1 = (const float*)d_in[3];
  const float* bfilm1 = (const float*)d_in[4];
  const float* Wskip1 = (const float*)d_in[5];
  const float* Wfs1 = (const float*)d_in[6];
  const float* Wlin2 = (const float*)d_in[7];
  const float* Wfilm2 = (const float*)d_in[8];
  const float* bfilm2 = (const float*)d_in[9];
  const float* Wskip2 = (const float*)d_in[10];
  const float* Wfs2 = (const float*)d_in[11];
  const float* Wout = (const float*)d_in[12];
  const float* bout = (const float*)d_in[13];

  int N = in_sizes[0] / 64;
  int E = in_sizes[1] / 2;
  const int* src = ei;
  const int* dst = ei + E;

  float* ws = (float*)d_ws;
  size_t NF = (size_t)N * 64;
  float* n1 = ws;            // L1: H   | then X2    | then AGG2
  float* n2 = n1 + NF;       // L1: BETA| L2: BETA   | then X3
  float* n3 = n2 + NF;       // GAMMA (both layers)
  float* n4 = n3 + NF;       // L1: S   | L2: H
  float* n5 = n4 + NF;       // L1: AGG | L2: S
  float* deg = n5 + NF;      // [N]

  int gemm_blocks = (N + 63) / 64;
  int edge_blocks = (int)(((long long)E * 64 + THREADS - 1) / THREADS);
  int fin_blocks = (int)(((size_t)N * 16 + THREADS - 1) / THREADS);
  int head_blocks = (N + 3) / 4;

  // degree (shared by both layers)
  hipMemsetAsync(deg, 0, (size_t)N * sizeof(float), stream);
  deg_kernel<<<(E + THREADS - 1) / THREADS, THREADS, 0, stream>>>(dst, deg, E);

  // ---- layer 1 ----
  gemm_node<0><<<gemm_blocks, THREADS, 0, stream>>>(
      x, N, Wlin1, 64, 0, Wfilm1, 128, 0, Wfilm1, 128, 64, bfilm1, n1, n2, n3);
  gemm_node<1><<<gemm_blocks, THREADS, 0, stream>>>(
      x, N, Wskip1, 64, 0, Wfs1, 128, 0, Wfs1, 128, 64, nullptr, n4, nullptr, nullptr);
  hipMemsetAsync(n5, 0, NF * sizeof(float), stream);
  edge_kernel<<<edge_blocks, THREADS, 0, stream>>>(n1, n3, n2, n5, src, dst, E);
  finalize_kernel<<<fin_blocks, THREADS, 0, stream>>>(n4, n5, deg, n1, N);  // X2 -> n1

  // ---- layer 2 ----
  gemm_node<0><<<gemm_blocks, THREADS, 0, stream>>>(
      n1, N, Wlin2, 64, 0, Wfilm2, 128, 0, Wfilm2, 128, 64, bfilm2, n4, n2, n3);
  gemm_node<1><<<gemm_blocks, THREADS, 0, stream>>>(
      n1, N, Wskip2, 64, 0, Wfs2, 128, 0, Wfs2, 128, 64, nullptr, n5, nullptr, nullptr);
  hipMemsetAsync(n1, 0, NF * sizeof(float), stream);
  edge_kernel<<<edge_blocks, THREADS, 0, stream>>>(n4, n3, n2, n1, src, dst, E);
  finalize_kernel<<<fin_blocks, THREADS, 0, stream>>>(n5, n1, deg, n2, N);  // X3 -> n2

  // ---- head ----
  head_kernel<<<head_blocks, THREADS, 0, stream>>>(n2, Wout, bout, (float*)d_out, N);
}

// Round 2
// 513.327 us; speedup vs baseline: 1.9879x; 1.9879x over previous
//
#include <hip/hip_runtime.h>
#include <cstddef>

// ---------------------------------------------------------------------------
// GraphFiLM: 2x FiLMConv(mean agg) + leaky_relu + linear head, fp32.
// Round 1: CSR-based dst-centric aggregation (no float atomics), fused
// finalize + head. N = 100000, D = 64, E = 1.6M.
// ---------------------------------------------------------------------------

#define THREADS 256

__device__ __forceinline__ void stage_w(float (*WT)[64], const float* __restrict__ W,
                                        int ld, int off, int t) {
  for (int q = t; q < 1024; q += THREADS) {
    int k = q >> 4;
    int c4 = q & 15;
    *(float4*)&WT[k][c4 * 4] = *(const float4*)(W + (size_t)k * ld + off + c4 * 4);
  }
}

__device__ __forceinline__ void gemm_pass(const float (*XT)[64], const float (*WT)[64],
                                          int m0, int c0, float acc[4][4]) {
#pragma unroll 4
  for (int k = 0; k < 64; ++k) {
    float4 xv = *(const float4*)&XT[k][m0];
    float4 wv = *(const float4*)&WT[k][c0];
    float xs[4] = {xv.x, xv.y, xv.z, xv.w};
    float ws[4] = {wv.x, wv.y, wv.z, wv.w};
#pragma unroll
    for (int i = 0; i < 4; ++i)
#pragma unroll
      for (int j = 0; j < 4; ++j)
        acc[i][j] = fmaf(xs[i], ws[j], acc[i][j]);
  }
}

// MODE 0: O0 = X@W0; O1 = X@W1 + bias[0:64]; O2 = X@W2 + bias[64:128]
// MODE 1: O0 = relu( (X@W2) * (X@W0) + (X@W1) )
template <int MODE>
__global__ __launch_bounds__(THREADS) void gemm_node(
    const float* __restrict__ X, int N,
    const float* __restrict__ W0, int ld0, int off0,
    const float* __restrict__ W1, int ld1, int off1,
    const float* __restrict__ W2, int ld2, int off2,
    const float* __restrict__ bias,
    float* __restrict__ O0, float* __restrict__ O1, float* __restrict__ O2) {
  __shared__ float XT[64][64];
  __shared__ float WT[64][64];
  int t = threadIdx.x;
  int row0 = blockIdx.x * 64;

  for (int q = t; q < 1024; q += THREADS) {
    int m = q >> 4;
    int k4 = q & 15;
    int gr = row0 + m;
    float4 v = make_float4(0.f, 0.f, 0.f, 0.f);
    if (gr < N) v = *(const float4*)(X + (size_t)gr * 64 + k4 * 4);
    XT[k4 * 4 + 0][m] = v.x;
    XT[k4 * 4 + 1][m] = v.y;
    XT[k4 * 4 + 2][m] = v.z;
    XT[k4 * 4 + 3][m] = v.w;
  }

  int m0 = (t & 15) * 4;
  int c0 = (t >> 4) * 4;

  float a0[4][4], a1[4][4], a2[4][4];
#pragma unroll
  for (int i = 0; i < 4; ++i)
#pragma unroll
    for (int j = 0; j < 4; ++j) {
      a0[i][j] = 0.f;
      a1[i][j] = 0.f;
      a2[i][j] = 0.f;
    }

  stage_w(WT, W0, ld0, off0, t);
  __syncthreads();
  gemm_pass(XT, WT, m0, c0, a0);
  __syncthreads();
  stage_w(WT, W1, ld1, off1, t);
  __syncthreads();
  gemm_pass(XT, WT, m0, c0, a1);
  __syncthreads();
  stage_w(WT, W2, ld2, off2, t);
  __syncthreads();
  gemm_pass(XT, WT, m0, c0, a2);

#pragma unroll
  for (int i = 0; i < 4; ++i) {
    int gr = row0 + m0 + i;
    if (gr >= N) continue;
    if (MODE == 0) {
      float4 h = {a0[i][0], a0[i][1], a0[i][2], a0[i][3]};
      float4 be = {a1[i][0] + bias[c0 + 0], a1[i][1] + bias[c0 + 1],
                   a1[i][2] + bias[c0 + 2], a1[i][3] + bias[c0 + 3]};
      float4 ga = {a2[i][0] + bias[64 + c0 + 0], a2[i][1] + bias[64 + c0 + 1],
                   a2[i][2] + bias[64 + c0 + 2], a2[i][3] + bias[64 + c0 + 3]};
      *(float4*)(O0 + (size_t)gr * 64 + c0) = h;
      *(float4*)(O1 + (size_t)gr * 64 + c0) = be;
      *(float4*)(O2 + (size_t)gr * 64 + c0) = ga;
    } else {
      float4 s;
      s.x = fmaxf(fmaf(a2[i][0], a0[i][0], a1[i][0]), 0.f);
      s.y = fmaxf(fmaf(a2[i][1], a0[i][1], a1[i][1]), 0.f);
      s.z = fmaxf(fmaf(a2[i][2], a0[i][2], a1[i][2]), 0.f);
      s.w = fmaxf(fmaf(a2[i][3], a0[i][3], a1[i][3]), 0.f);
      *(float4*)(O0 + (size_t)gr * 64 + c0) = s;
    }
  }
}

// ---------------- CSR build ----------------

__global__ __launch_bounds__(THREADS) void deg_count(const int* __restrict__ dst,
                                                     int* __restrict__ degc, int E) {
  int e = blockIdx.x * THREADS + threadIdx.x;
  if (e < E) atomicAdd(&degc[dst[e]], 1);
}

// each block scans 1024 elements (256 threads x 4); writes per-element
// exclusive-within-block scan + block total
__global__ __launch_bounds__(THREADS) void scan_block(const int* __restrict__ degc,
                                                      int* __restrict__ excl,
                                                      int* __restrict__ bsums, int N) {
  __shared__ int ts[THREADS];
  int t = threadIdx.x;
  int base = blockIdx.x * 1024 + t * 4;
  int v0 = 0, v1 = 0, v2 = 0, v3 = 0;
  if (base + 0 < N) v0 = degc[base + 0];
  if (base + 1 < N) v1 = degc[base + 1];
  if (base + 2 < N) v2 = degc[base + 2];
  if (base + 3 < N) v3 = degc[base + 3];
  int s = v0 + v1 + v2 + v3;
  ts[t] = s;
  __syncthreads();
  for (int off = 1; off < THREADS; off <<= 1) {
    int x = (t >= off) ? ts[t - off] : 0;
    __syncthreads();
    ts[t] += x;
    __syncthreads();
  }
  int eb = ts[t] - s;  // exclusive base for this thread
  if (base + 0 < N) excl[base + 0] = eb;
  if (base + 1 < N) excl[base + 1] = eb + v0;
  if (base + 2 < N) excl[base + 2] = eb + v0 + v1;
  if (base + 3 < N) excl[base + 3] = eb + v0 + v1 + v2;
  if (t == THREADS - 1) bsums[blockIdx.x] = ts[t];
}

__global__ void scan_tops(int* __restrict__ bsums, int nb) {
  if (threadIdx.x == 0 && blockIdx.x == 0) {
    int run = 0;
    for (int i = 0; i < nb; ++i) {
      int x = bsums[i];
      bsums[i] = run;
      run += x;
    }
  }
}

__global__ __launch_bounds__(THREADS) void scan_fix(int* __restrict__ rs,
                                                    const int* __restrict__ bsums,
                                                    int N, int E) {
  int i = blockIdx.x * THREADS + threadIdx.x;
  if (i < N) rs[i] += bsums[i >> 10];
  if (i == 0) rs[N] = E;
}

__global__ __launch_bounds__(THREADS) void scatter_edges(
    const int* __restrict__ src, const int* __restrict__ dst,
    const int* __restrict__ rs, int* __restrict__ cursor,
    int* __restrict__ csr, int E) {
  int e = blockIdx.x * THREADS + threadIdx.x;
  if (e < E) {
    int d = dst[e];
    int p = atomicAdd(&cursor[d], 1);
    csr[rs[d] + p] = src[e];
  }
}

// ---------------- dst-centric aggregation (fused finalize [+head]) ----------

template <int FINAL>
__global__ __launch_bounds__(THREADS) void agg_kernel(
    const float* __restrict__ H, const float* __restrict__ GAMMA,
    const float* __restrict__ BETA, const float* __restrict__ S,
    const int* __restrict__ rs, const int* __restrict__ csr,
    float* __restrict__ Xn, const float* __restrict__ Wout,
    const float* __restrict__ bout, float* __restrict__ out, int N) {
  int node = blockIdx.x * 4 + (threadIdx.x >> 6);
  int lane = threadIdx.x & 63;
  if (node >= N) return;
  int beg = rs[node], end = rs[node + 1];
  size_t no = (size_t)node * 64 + lane;
  float g = GAMMA[no], b = BETA[no];
  float acc = 0.f;
  int i = beg;
  for (; i + 4 <= end; i += 4) {
    int s0 = csr[i], s1 = csr[i + 1], s2 = csr[i + 2], s3 = csr[i + 3];
    float h0 = H[(size_t)s0 * 64 + lane];
    float h1 = H[(size_t)s1 * 64 + lane];
    float h2 = H[(size_t)s2 * 64 + lane];
    float h3 = H[(size_t)s3 * 64 + lane];
    acc += fmaxf(fmaf(g, h0, b), 0.f);
    acc += fmaxf(fmaf(g, h1, b), 0.f);
    acc += fmaxf(fmaf(g, h2, b), 0.f);
    acc += fmaxf(fmaf(g, h3, b), 0.f);
  }
  for (; i < end; ++i) {
    float h0 = H[(size_t)csr[i] * 64 + lane];
    acc += fmaxf(fmaf(g, h0, b), 0.f);
  }
  float inv = 1.f / fmaxf((float)(end - beg), 1.f);
  float v = fmaf(acc, inv, S[no]);
  v = v > 0.f ? v : 0.01f * v;
  if (FINAL == 0) {
    Xn[no] = v;
  } else {
    v *= Wout[lane];
#pragma unroll
    for (int off = 32; off; off >>= 1) v += __shfl_xor(v, off, 64);
    if (lane == 0) out[node] = v + bout[0];
  }
}

extern "C" void kernel_launch(void* const* d_in, const int* in_sizes, int n_in,
                              void* d_out, int out_size, void* d_ws, size_t ws_size,
                              hipStream_t stream) {
  const float* x = (const float*)d_in[0];
  const int* ei = (const int*)d_in[1];
  const float* Wlin1 = (const float*)d_in[2];
  const float* Wfilm1 = (const float*)d_in[3];
  const float* bfilm1 = (const float*)d_in[4];
  const float* Wskip1 = (const float*)d_in[5];
  const float* Wfs1 = (const float*)d_in[6];
  const float* Wlin2 = (const float*)d_in[7];
  const float* Wfilm2 = (const float*)d_in[8];
  const float* bfilm2 = (const float*)d_in[9];
  const float* Wskip2 = (const float*)d_in[10];
  const float* Wfs2 = (const float*)d_in[11];
  const float* Wout = (const float*)d_in[12];
  const float* bout = (const float*)d_in[13];

  int N = in_sizes[0] / 64;
  int E = in_sizes[1] / 2;
  const int* src = ei;
  const int* dst = ei + E;

  float* ws = (float*)d_ws;
  size_t NF = (size_t)N * 64;
  float* n1 = ws;        // H
  float* n2 = n1 + NF;   // BETA
  float* n3 = n2 + NF;   // GAMMA
  float* n4 = n3 + NF;   // S (skip)
  float* n5 = n4 + NF;   // X2
  int* ib = (int*)(n5 + NF);
  int* degc = ib;             // [N]   deg counts, reused as scatter cursor
  int* rs = degc + N;         // [N+1] row starts (excl scan in place)
  int* bsums = rs + (N + 1);  // [<=128]
  int* csr = bsums + 128;     // [E]   src ids bucketed by dst

  int gemm_blocks = (N + 63) / 64;
  int eblocks = (E + THREADS - 1) / THREADS;
  int nb = (N + 1023) / 1024;
  int agg_blocks = (N + 3) / 4;

  // ---- CSR build (shared by both layers) ----
  hipMemsetAsync(degc, 0, (size_t)N * sizeof(int), stream);
  deg_count<<<eblocks, THREADS, 0, stream>>>(dst, degc, E);
  scan_block<<<nb, THREADS, 0, stream>>>(degc, rs, bsums, N);
  scan_tops<<<1, 64, 0, stream>>>(bsums, nb);
  scan_fix<<<(N + THREADS - 1) / THREADS, THREADS, 0, stream>>>(rs, bsums, N, E);
  hipMemsetAsync(degc, 0, (size_t)N * sizeof(int), stream);
  scatter_edges<<<eblocks, THREADS, 0, stream>>>(src, dst, rs, degc, csr, E);

  // ---- layer 1 ----
  gemm_node<0><<<gemm_blocks, THREADS, 0, stream>>>(
      x, N, Wlin1, 64, 0, Wfilm1, 128, 0, Wfilm1, 128, 64, bfilm1, n1, n2, n3);
  gemm_node<1><<<gemm_blocks, THREADS, 0, stream>>>(
      x, N, Wskip1, 64, 0, Wfs1, 128, 0, Wfs1, 128, 64, nullptr, n4, nullptr, nullptr);
  agg_kernel<0><<<agg_blocks, THREADS, 0, stream>>>(
      n1, n3, n2, n4, rs, csr, n5, nullptr, nullptr, nullptr, N);

  // ---- layer 2 ----
  gemm_node<0><<<gemm_blocks, THREADS, 0, stream>>>(
      n5, N, Wlin2, 64, 0, Wfilm2, 128, 0, Wfilm2, 128, 64, bfilm2, n1, n2, n3);
  gemm_node<1><<<gemm_blocks, THREADS, 0, stream>>>(
      n5, N, Wskip2, 64, 0, Wfs2, 128, 0, Wfs2, 128, 64, nullptr, n4, nullptr, nullptr);
  agg_kernel<1><<<agg_blocks, THREADS, 0, stream>>>(
      n1, n3, n2, n4, rs, csr, nullptr, Wout, bout, (float*)d_out, N);
}

// Round 3
// 390.783 us; speedup vs baseline: 2.6113x; 1.3136x over previous
//
#include <hip/hip_runtime.h>
#include <cstddef>

// ---------------------------------------------------------------------------
// GraphFiLM: 2x FiLMConv(mean agg) + leaky_relu + linear head, fp32.
// Round 2: atomic-free bucketed CSR build (LDS counting sort, localized
// writes) replacing the global-atomic scatter. N=100000, D=64, E=1.6M.
// ---------------------------------------------------------------------------

#define THREADS 256
#define NB 256      // number of edge-chunk blocks for histogram/scatter
#define NPSHIFT 9   // 512 nodes per partition
#define NPSZ 512

// ---------------- GEMM (unchanged from round 1) ----------------

__device__ __forceinline__ void stage_w(float (*WT)[64], const float* __restrict__ W,
                                        int ld, int off, int t) {
  for (int q = t; q < 1024; q += THREADS) {
    int k = q >> 4;
    int c4 = q & 15;
    *(float4*)&WT[k][c4 * 4] = *(const float4*)(W + (size_t)k * ld + off + c4 * 4);
  }
}

__device__ __forceinline__ void gemm_pass(const float (*XT)[64], const float (*WT)[64],
                                          int m0, int c0, float acc[4][4]) {
#pragma unroll 4
  for (int k = 0; k < 64; ++k) {
    float4 xv = *(const float4*)&XT[k][m0];
    float4 wv = *(const float4*)&WT[k][c0];
    float xs[4] = {xv.x, xv.y, xv.z, xv.w};
    float ws[4] = {wv.x, wv.y, wv.z, wv.w};
#pragma unroll
    for (int i = 0; i < 4; ++i)
#pragma unroll
      for (int j = 0; j < 4; ++j)
        acc[i][j] = fmaf(xs[i], ws[j], acc[i][j]);
  }
}

// MODE 0: O0 = X@W0; O1 = X@W1 + bias[0:64]; O2 = X@W2 + bias[64:128]
// MODE 1: O0 = relu( (X@W2) * (X@W0) + (X@W1) )
template <int MODE>
__global__ __launch_bounds__(THREADS) void gemm_node(
    const float* __restrict__ X, int N,
    const float* __restrict__ W0, int ld0, int off0,
    const float* __restrict__ W1, int ld1, int off1,
    const float* __restrict__ W2, int ld2, int off2,
    const float* __restrict__ bias,
    float* __restrict__ O0, float* __restrict__ O1, float* __restrict__ O2) {
  __shared__ float XT[64][64];
  __shared__ float WT[64][64];
  int t = threadIdx.x;
  int row0 = blockIdx.x * 64;

  for (int q = t; q < 1024; q += THREADS) {
    int m = q >> 4;
    int k4 = q & 15;
    int gr = row0 + m;
    float4 v = make_float4(0.f, 0.f, 0.f, 0.f);
    if (gr < N) v = *(const float4*)(X + (size_t)gr * 64 + k4 * 4);
    XT[k4 * 4 + 0][m] = v.x;
    XT[k4 * 4 + 1][m] = v.y;
    XT[k4 * 4 + 2][m] = v.z;
    XT[k4 * 4 + 3][m] = v.w;
  }

  int m0 = (t & 15) * 4;
  int c0 = (t >> 4) * 4;

  float a0[4][4], a1[4][4], a2[4][4];
#pragma unroll
  for (int i = 0; i < 4; ++i)
#pragma unroll
    for (int j = 0; j < 4; ++j) {
      a0[i][j] = 0.f;
      a1[i][j] = 0.f;
      a2[i][j] = 0.f;
    }

  stage_w(WT, W0, ld0, off0, t);
  __syncthreads();
  gemm_pass(XT, WT, m0, c0, a0);
  __syncthreads();
  stage_w(WT, W1, ld1, off1, t);
  __syncthreads();
  gemm_pass(XT, WT, m0, c0, a1);
  __syncthreads();
  stage_w(WT, W2, ld2, off2, t);
  __syncthreads();
  gemm_pass(XT, WT, m0, c0, a2);

#pragma unroll
  for (int i = 0; i < 4; ++i) {
    int gr = row0 + m0 + i;
    if (gr >= N) continue;
    if (MODE == 0) {
      float4 h = {a0[i][0], a0[i][1], a0[i][2], a0[i][3]};
      float4 be = {a1[i][0] + bias[c0 + 0], a1[i][1] + bias[c0 + 1],
                   a1[i][2] + bias[c0 + 2], a1[i][3] + bias[c0 + 3]};
      float4 ga = {a2[i][0] + bias[64 + c0 + 0], a2[i][1] + bias[64 + c0 + 1],
                   a2[i][2] + bias[64 + c0 + 2], a2[i][3] + bias[64 + c0 + 3]};
      *(float4*)(O0 + (size_t)gr * 64 + c0) = h;
      *(float4*)(O1 + (size_t)gr * 64 + c0) = be;
      *(float4*)(O2 + (size_t)gr * 64 + c0) = ga;
    } else {
      float4 s;
      s.x = fmaxf(fmaf(a2[i][0], a0[i][0], a1[i][0]), 0.f);
      s.y = fmaxf(fmaf(a2[i][1], a0[i][1], a1[i][1]), 0.f);
      s.z = fmaxf(fmaf(a2[i][2], a0[i][2], a1[i][2]), 0.f);
      s.w = fmaxf(fmaf(a2[i][3], a0[i][3], a1[i][3]), 0.f);
      *(float4*)(O0 + (size_t)gr * 64 + c0) = s;
    }
  }
}

// ---------------- CSR build: bucketed counting sort ----------------
// P = ceil(N/512) partitions (<= 256 for N <= 131072).

// phase 1: per-block partition histogram -> counts[p * NB + b]
__global__ __launch_bounds__(THREADS) void hist_part(const int* __restrict__ dst,
                                                     int* __restrict__ counts,
                                                     int E, int CH, int P) {
  __shared__ int h[256];
  int b = blockIdx.x, t = threadIdx.x;
  h[t] = 0;
  __syncthreads();
  int lo = b * CH;
  int hi = min(lo + CH, E);
  for (int i = lo + t; i < hi; i += THREADS) atomicAdd(&h[dst[i] >> NPSHIFT], 1);
  __syncthreads();
  if (t < P) counts[t * NB + b] = h[t];
}

// hierarchical exclusive scan (in place), 1024 elems / block
__global__ __launch_bounds__(THREADS) void scan_block(int* __restrict__ arr,
                                                      int* __restrict__ bsums, int M) {
  __shared__ int ts[THREADS];
  int t = threadIdx.x;
  int base = blockIdx.x * 1024 + t * 4;
  int v0 = 0, v1 = 0, v2 = 0, v3 = 0;
  if (base + 0 < M) v0 = arr[base + 0];
  if (base + 1 < M) v1 = arr[base + 1];
  if (base + 2 < M) v2 = arr[base + 2];
  if (base + 3 < M) v3 = arr[base + 3];
  int s = v0 + v1 + v2 + v3;
  ts[t] = s;
  __syncthreads();
  for (int off = 1; off < THREADS; off <<= 1) {
    int x = (t >= off) ? ts[t - off] : 0;
    __syncthreads();
    ts[t] += x;
    __syncthreads();
  }
  int eb = ts[t] - s;
  if (base + 0 < M) arr[base + 0] = eb;
  if (base + 1 < M) arr[base + 1] = eb + v0;
  if (base + 2 < M) arr[base + 2] = eb + v0 + v1;
  if (base + 3 < M) arr[base + 3] = eb + v0 + v1 + v2;
  if (t == THREADS - 1) bsums[blockIdx.x] = ts[t];
}

__global__ void scan_tops(int* __restrict__ bsums, int nb) {
  if (threadIdx.x == 0 && blockIdx.x == 0) {
    int run = 0;
    for (int i = 0; i < nb; ++i) {
      int x = bsums[i];
      bsums[i] = run;
      run += x;
    }
  }
}

__global__ __launch_bounds__(THREADS) void scan_fix(int* __restrict__ arr,
                                                    const int* __restrict__ bsums,
                                                    int M, int TOT) {
  int i = blockIdx.x * THREADS + threadIdx.x;
  if (i < M) arr[i] += bsums[i >> 10];
  if (i == 0) arr[M] = TOT;
}

// phase 3: scatter (src,dst) pairs into partition-bucketed order
__global__ __launch_bounds__(THREADS) void bucket_scatter(
    const int* __restrict__ src, const int* __restrict__ dst,
    const int* __restrict__ base, int2* __restrict__ buck, int E, int CH, int P) {
  __shared__ int cur[256];
  int b = blockIdx.x, t = threadIdx.x;
  if (t < P) cur[t] = base[t * NB + b];
  __syncthreads();
  int lo = b * CH;
  int hi = min(lo + CH, E);
  for (int i = lo + t; i < hi; i += THREADS) {
    int d = dst[i];
    int pos = atomicAdd(&cur[d >> NPSHIFT], 1);
    buck[pos] = make_int2(src[i], d);
  }
}

// phase 4: one block per partition; LDS histogram + scan -> rs, csr
__global__ __launch_bounds__(THREADS) void build_csr(
    const int2* __restrict__ buck, const int* __restrict__ base,
    int* __restrict__ rs, int* __restrict__ csr, int N, int E, int P) {
  __shared__ int hA[NPSZ], hB[NPSZ], cur[NPSZ];
  int p = blockIdx.x, t = threadIdx.x;
  hA[t] = 0;
  hA[t + 256] = 0;
  __syncthreads();
  int pstart = base[p * NB];
  int pend = base[(p + 1) * NB];  // base[P*NB] == E for last partition
  for (int i = pstart + t; i < pend; i += THREADS)
    atomicAdd(&hA[buck[i].y & (NPSZ - 1)], 1);
  __syncthreads();
  // inclusive Hillis-Steele scan over 512 bins (double buffer)
  int* s = hA;
  int* d2 = hB;
  for (int off = 1; off < NPSZ; off <<= 1) {
#pragma unroll
    for (int r = 0; r < 2; ++r) {
      int idx = t + r * 256;
      int v = s[idx];
      if (idx >= off) v += s[idx - off];
      d2[idx] = v;
    }
    __syncthreads();
    int* tmp = s;
    s = d2;
    d2 = tmp;
  }
#pragma unroll
  for (int r = 0; r < 2; ++r) {
    int idx = t + r * 256;
    int excl = idx ? s[idx - 1] : 0;
    cur[idx] = excl;
    int node = (p << NPSHIFT) + idx;
    if (node < N) rs[node] = pstart + excl;
  }
  if (p == P - 1 && t == 0) rs[N] = E;
  __syncthreads();
  for (int i = pstart + t; i < pend; i += THREADS) {
    int2 e = buck[i];
    int pos = atomicAdd(&cur[e.y & (NPSZ - 1)], 1);
    csr[pstart + pos] = e.x;
  }
}

// ---------------- dst-centric aggregation (fused finalize [+head]) ----------

template <int FINAL>
__global__ __launch_bounds__(THREADS) void agg_kernel(
    const float* __restrict__ H, const float* __restrict__ GAMMA,
    const float* __restrict__ BETA, const float* __restrict__ S,
    const int* __restrict__ rs, const int* __restrict__ csr,
    float* __restrict__ Xn, const float* __restrict__ Wout,
    const float* __restrict__ bout, float* __restrict__ out, int N) {
  int node = blockIdx.x * 4 + (threadIdx.x >> 6);
  int lane = threadIdx.x & 63;
  if (node >= N) return;
  int beg = rs[node], end = rs[node + 1];
  size_t no = (size_t)node * 64 + lane;
  float g = GAMMA[no], b = BETA[no];
  float acc = 0.f;
  int i = beg;
  for (; i + 4 <= end; i += 4) {
    int s0 = csr[i], s1 = csr[i + 1], s2 = csr[i + 2], s3 = csr[i + 3];
    float h0 = H[(size_t)s0 * 64 + lane];
    float h1 = H[(size_t)s1 * 64 + lane];
    float h2 = H[(size_t)s2 * 64 + lane];
    float h3 = H[(size_t)s3 * 64 + lane];
    acc += fmaxf(fmaf(g, h0, b), 0.f);
    acc += fmaxf(fmaf(g, h1, b), 0.f);
    acc += fmaxf(fmaf(g, h2, b), 0.f);
    acc += fmaxf(fmaf(g, h3, b), 0.f);
  }
  for (; i < end; ++i) {
    float h0 = H[(size_t)csr[i] * 64 + lane];
    acc += fmaxf(fmaf(g, h0, b), 0.f);
  }
  float inv = 1.f / fmaxf((float)(end - beg), 1.f);
  float v = fmaf(acc, inv, S[no]);
  v = v > 0.f ? v : 0.01f * v;
  if (FINAL == 0) {
    Xn[no] = v;
  } else {
    v *= Wout[lane];
#pragma unroll
    for (int off = 32; off; off >>= 1) v += __shfl_xor(v, off, 64);
    if (lane == 0) out[node] = v + bout[0];
  }
}

extern "C" void kernel_launch(void* const* d_in, const int* in_sizes, int n_in,
                              void* d_out, int out_size, void* d_ws, size_t ws_size,
                              hipStream_t stream) {
  const float* x = (const float*)d_in[0];
  const int* ei = (const int*)d_in[1];
  const float* Wlin1 = (const float*)d_in[2];
  const float* Wfilm1 = (const float*)d_in[3];
  const float* bfilm1 = (const float*)d_in[4];
  const float* Wskip1 = (const float*)d_in[5];
  const float* Wfs1 = (const float*)d_in[6];
  const float* Wlin2 = (const float*)d_in[7];
  const float* Wfilm2 = (const float*)d_in[8];
  const float* bfilm2 = (const float*)d_in[9];
  const float* Wskip2 = (const float*)d_in[10];
  const float* Wfs2 = (const float*)d_in[11];
  const float* Wout = (const float*)d_in[12];
  const float* bout = (const float*)d_in[13];

  int N = in_sizes[0] / 64;
  int E = in_sizes[1] / 2;
  const int* src = ei;
  const int* dst = ei + E;

  int P = (N + NPSZ - 1) >> NPSHIFT;  // partitions (196 for N=100000)
  int CH = (E + NB - 1) / NB;         // edges per histogram block
  int M = P * NB;                     // counts elements

  float* ws = (float*)d_ws;
  size_t NF = (size_t)N * 64;
  float* n1 = ws;        // H
  float* n2 = n1 + NF;   // BETA
  float* n3 = n2 + NF;   // GAMMA
  float* n4 = n3 + NF;   // S (skip)
  float* n5 = n4 + NF;   // X2 (aliased as buck during CSR build)
  int* rs = (int*)(n5 + NF);   // [N+1]
  int* csr = rs + (N + 2);     // [E]
  int* counts = csr + E;       // [M+1]
  int* bsums = counts + (M + 2);  // [<=128]
  int2* buck = (int2*)n5;      // [E] pairs; dead before agg<0> writes X2

  int gemm_blocks = (N + 63) / 64;
  int agg_blocks = (N + 3) / 4;
  int nbM = (M + 1023) / 1024;

  // ---- CSR build (atomic-free at global scope, localized writes) ----
  hist_part<<<NB, THREADS, 0, stream>>>(dst, counts, E, CH, P);
  scan_block<<<nbM, THREADS, 0, stream>>>(counts, bsums, M);
  scan_tops<<<1, 64, 0, stream>>>(bsums, nbM);
  scan_fix<<<(M + THREADS - 1) / THREADS, THREADS, 0, stream>>>(counts, bsums, M, E);
  bucket_scatter<<<NB, THREADS, 0, stream>>>(src, dst, counts, buck, E, CH, P);
  build_csr<<<P, THREADS, 0, stream>>>(buck, counts, rs, csr, N, E, P);

  // ---- layer 1 ----
  gemm_node<0><<<gemm_blocks, THREADS, 0, stream>>>(
      x, N, Wlin1, 64, 0, Wfilm1, 128, 0, Wfilm1, 128, 64, bfilm1, n1, n2, n3);
  gemm_node<1><<<gemm_blocks, THREADS, 0, stream>>>(
      x, N, Wskip1, 64, 0, Wfs1, 128, 0, Wfs1, 128, 64, nullptr, n4, nullptr, nullptr);
  agg_kernel<0><<<agg_blocks, THREADS, 0, stream>>>(
      n1, n3, n2, n4, rs, csr, n5, nullptr, nullptr, nullptr, N);

  // ---- layer 2 ----
  gemm_node<0><<<gemm_blocks, THREADS, 0, stream>>>(
      n5, N, Wlin2, 64, 0, Wfilm2, 128, 0, Wfilm2, 128, 64, bfilm2, n1, n2, n3);
  gemm_node<1><<<gemm_blocks, THREADS, 0, stream>>>(
      n5, N, Wskip2, 64, 0, Wfs2, 128, 0, Wfs2, 128, 64, nullptr, n4, nullptr, nullptr);
  agg_kernel<1><<<agg_blocks, THREADS, 0, stream>>>(
      n1, n3, n2, n4, rs, csr, nullptr, Wout, bout, (float*)d_out, N);
}

// Round 5
// 266.318 us; speedup vs baseline: 3.8316x; 1.4674x over previous
//
#include <hip/hip_runtime.h>
#include <cstddef>

// ---------------------------------------------------------------------------
// GraphFiLM: 2x FiLMConv(mean agg) + leaky_relu + linear head.
// Round 4: fix R3's W-tile LDS staging (1536 -> 3072 uint4; only half the
// 6-matrix tile was staged -> NaN from uninitialized LDS). Otherwise R3.
// ---------------------------------------------------------------------------

#define THREADS 256
#define NB 256
#define NPSHIFT 9
#define NPSZ 512

typedef unsigned short u16;
typedef unsigned int u32;
typedef short bf16x8 __attribute__((ext_vector_type(8)));
typedef float f32x4 __attribute__((ext_vector_type(4)));

__device__ __forceinline__ u16 f2b(float f) {
  u32 u = __float_as_uint(f);
  u32 r = (u + 0x7FFFu + ((u >> 16) & 1u)) >> 16;
  return (u16)r;
}
__device__ __forceinline__ float b2f(u16 u) {
  return __uint_as_float(((u32)u) << 16);
}

// ---------------- weight prep: W^T, bf16, swizzled ----------------
struct WSrc {
  const float* p;
  int ld;
  int off;
};
struct WPack {
  WSrc m[12];
};

// block b handles matrix b: out[b][n][k] = bf16(W[k][off+n]), elem-swizzled
__global__ __launch_bounds__(THREADS) void prep_w(WPack wp, u16* __restrict__ Wp) {
  int b = blockIdx.x, t = threadIdx.x;
  WSrc ws = wp.m[b];
  u16* dst = Wp + b * 4096;
#pragma unroll
  for (int i = 0; i < 16; ++i) {
    int e = t + 256 * i;
    int n = e >> 6, k = e & 63;
    float v = ws.p[(size_t)k * ws.ld + ws.off + n];
    dst[e ^ ((n & 7) << 3)] = f2b(v);
  }
}

// ---------------- fused 6-matmul MFMA GEMM per layer ----------------
// mats 0..2: skip, fs_beta, fs_gamma -> S = relu(fsg*skip + fsb)   (fp32)
// mats 3..5: lin, film_beta, film_gamma -> H, BETA+bias, GAMMA+bias (bf16)
template <int INBF16>
__global__ __launch_bounds__(THREADS) void gemm_mfma(
    const void* __restrict__ Xv, int N, const u16* __restrict__ WpL,
    const float* __restrict__ bfilm, u16* __restrict__ H, u16* __restrict__ BETA,
    u16* __restrict__ GAMMA, float* __restrict__ S) {
  __shared__ u16 XT[64 * 64];      // [row][k] bf16, elem-swizzled
  __shared__ u16 WT[6 * 64 * 64];  // [mat][n][k] bf16, elem-swizzled
  int t = threadIdx.x;
  int row0 = blockIdx.x * 64;

  // stage X tile (fp32->bf16 or direct bf16), swizzled
  {
    int row = t >> 2, kq = (t & 3) * 16;
    int gr = row0 + row;
    uint4 w0 = {0, 0, 0, 0}, w1 = {0, 0, 0, 0};
    if (gr < N) {
      if (INBF16) {
        const uint4* xp = (const uint4*)((const u16*)Xv + (size_t)gr * 64 + kq);
        w0 = xp[0];
        w1 = xp[1];
      } else {
        const float* xp = (const float*)Xv + (size_t)gr * 64 + kq;
        float4 f0 = ((const float4*)xp)[0];
        float4 f1 = ((const float4*)xp)[1];
        float4 f2 = ((const float4*)xp)[2];
        float4 f3 = ((const float4*)xp)[3];
        w0.x = f2b(f0.x) | ((u32)f2b(f0.y) << 16);
        w0.y = f2b(f0.z) | ((u32)f2b(f0.w) << 16);
        w0.z = f2b(f1.x) | ((u32)f2b(f1.y) << 16);
        w0.w = f2b(f1.z) | ((u32)f2b(f1.w) << 16);
        w1.x = f2b(f2.x) | ((u32)f2b(f2.y) << 16);
        w1.y = f2b(f2.z) | ((u32)f2b(f2.w) << 16);
        w1.z = f2b(f3.x) | ((u32)f2b(f3.y) << 16);
        w1.w = f2b(f3.z) | ((u32)f2b(f3.w) << 16);
      }
    }
    int e = row * 64 + kq;
    int s = (row & 7) << 3;
    *(uint4*)&XT[e ^ s] = w0;
    *(uint4*)&XT[(e + 8) ^ s] = w1;
  }
  // stage W (already prepped: straight copy). 6*4096 u16 = 3072 uint4.
  {
    const uint4* wsrc = (const uint4*)WpL;
    uint4* wdst = (uint4*)WT;
    for (int i = t; i < 3072; i += THREADS) wdst[i] = wsrc[i];
  }
  __syncthreads();

  int lane = t & 63, wid = t >> 6;
  int arow = wid * 16 + (lane & 15);
  int kb = (lane >> 4) << 3;
  int as = (arow & 7) << 3;
  bf16x8 A0 = *(const bf16x8*)&XT[(arow * 64 + kb) ^ as];
  bf16x8 A1 = *(const bf16x8*)&XT[(arow * 64 + 32 + kb) ^ as];

  auto bfrag = [&](int mat, int ct, int kk) -> bf16x8 {
    int n = ct * 16 + (lane & 15);
    int e = (n * 64 + kk * 32 + kb) ^ ((n & 7) << 3);
    return *(const bf16x8*)&WT[mat * 4096 + e];
  };

  const f32x4 z = {0.f, 0.f, 0.f, 0.f};
  int rbase = wid * 16 + ((lane >> 4) << 2);
  int cbase = lane & 15;

  // ---- trio 0: skip path -> S ----
  {
    f32x4 a0[4], a1[4], a2[4];
#pragma unroll
    for (int ct = 0; ct < 4; ++ct) {
      a0[ct] = z;
      a1[ct] = z;
      a2[ct] = z;
    }
#pragma unroll
    for (int ct = 0; ct < 4; ++ct) {
      a0[ct] = __builtin_amdgcn_mfma_f32_16x16x32_bf16(A0, bfrag(0, ct, 0), a0[ct], 0, 0, 0);
      a0[ct] = __builtin_amdgcn_mfma_f32_16x16x32_bf16(A1, bfrag(0, ct, 1), a0[ct], 0, 0, 0);
      a1[ct] = __builtin_amdgcn_mfma_f32_16x16x32_bf16(A0, bfrag(1, ct, 0), a1[ct], 0, 0, 0);
      a1[ct] = __builtin_amdgcn_mfma_f32_16x16x32_bf16(A1, bfrag(1, ct, 1), a1[ct], 0, 0, 0);
      a2[ct] = __builtin_amdgcn_mfma_f32_16x16x32_bf16(A0, bfrag(2, ct, 0), a2[ct], 0, 0, 0);
      a2[ct] = __builtin_amdgcn_mfma_f32_16x16x32_bf16(A1, bfrag(2, ct, 1), a2[ct], 0, 0, 0);
    }
#pragma unroll
    for (int ct = 0; ct < 4; ++ct) {
      int c = ct * 16 + cbase;
#pragma unroll
      for (int r = 0; r < 4; ++r) {
        int gr = row0 + rbase + r;
        if (gr < N) {
          float v = fmaxf(fmaf(a2[ct][r], a0[ct][r], a1[ct][r]), 0.f);
          S[(size_t)gr * 64 + c] = v;
        }
      }
    }
  }

  // ---- trio 1: film path -> H, BETA, GAMMA ----
  {
    f32x4 a0[4], a1[4], a2[4];
#pragma unroll
    for (int ct = 0; ct < 4; ++ct) {
      a0[ct] = z;
      a1[ct] = z;
      a2[ct] = z;
    }
#pragma unroll
    for (int ct = 0; ct < 4; ++ct) {
      a0[ct] = __builtin_amdgcn_mfma_f32_16x16x32_bf16(A0, bfrag(3, ct, 0), a0[ct], 0, 0, 0);
      a0[ct] = __builtin_amdgcn_mfma_f32_16x16x32_bf16(A1, bfrag(3, ct, 1), a0[ct], 0, 0, 0);
      a1[ct] = __builtin_amdgcn_mfma_f32_16x16x32_bf16(A0, bfrag(4, ct, 0), a1[ct], 0, 0, 0);
      a1[ct] = __builtin_amdgcn_mfma_f32_16x16x32_bf16(A1, bfrag(4, ct, 1), a1[ct], 0, 0, 0);
      a2[ct] = __builtin_amdgcn_mfma_f32_16x16x32_bf16(A0, bfrag(5, ct, 0), a2[ct], 0, 0, 0);
      a2[ct] = __builtin_amdgcn_mfma_f32_16x16x32_bf16(A1, bfrag(5, ct, 1), a2[ct], 0, 0, 0);
    }
#pragma unroll
    for (int ct = 0; ct < 4; ++ct) {
      int c = ct * 16 + cbase;
      float bb = bfilm[c];
      float bg = bfilm[64 + c];
#pragma unroll
      for (int r = 0; r < 4; ++r) {
        int gr = row0 + rbase + r;
        if (gr < N) {
          size_t o = (size_t)gr * 64 + c;
          H[o] = f2b(a0[ct][r]);
          BETA[o] = f2b(a1[ct][r] + bb);
          GAMMA[o] = f2b(a2[ct][r] + bg);
        }
      }
    }
  }
}

// ---------------- CSR build: bucketed counting sort (unchanged) -------------

__global__ __launch_bounds__(THREADS) void hist_part(const int* __restrict__ dst,
                                                     int* __restrict__ counts,
                                                     int E, int CH, int P) {
  __shared__ int h[256];
  int b = blockIdx.x, t = threadIdx.x;
  h[t] = 0;
  __syncthreads();
  int lo = b * CH;
  int hi = min(lo + CH, E);
  for (int i = lo + t; i < hi; i += THREADS) atomicAdd(&h[dst[i] >> NPSHIFT], 1);
  __syncthreads();
  if (t < P) counts[t * NB + b] = h[t];
}

__global__ __launch_bounds__(THREADS) void scan_block(int* __restrict__ arr,
                                                      int* __restrict__ bsums, int M) {
  __shared__ int ts[THREADS];
  int t = threadIdx.x;
  int base = blockIdx.x * 1024 + t * 4;
  int v0 = 0, v1 = 0, v2 = 0, v3 = 0;
  if (base + 0 < M) v0 = arr[base + 0];
  if (base + 1 < M) v1 = arr[base + 1];
  if (base + 2 < M) v2 = arr[base + 2];
  if (base + 3 < M) v3 = arr[base + 3];
  int s = v0 + v1 + v2 + v3;
  ts[t] = s;
  __syncthreads();
  for (int off = 1; off < THREADS; off <<= 1) {
    int x = (t >= off) ? ts[t - off] : 0;
    __syncthreads();
    ts[t] += x;
    __syncthreads();
  }
  int eb = ts[t] - s;
  if (base + 0 < M) arr[base + 0] = eb;
  if (base + 1 < M) arr[base + 1] = eb + v0;
  if (base + 2 < M) arr[base + 2] = eb + v0 + v1;
  if (base + 3 < M) arr[base + 3] = eb + v0 + v1 + v2;
  if (t == THREADS - 1) bsums[blockIdx.x] = ts[t];
}

__global__ void scan_tops(int* __restrict__ bsums, int nb) {
  if (threadIdx.x == 0 && blockIdx.x == 0) {
    int run = 0;
    for (int i = 0; i < nb; ++i) {
      int x = bsums[i];
      bsums[i] = run;
      run += x;
    }
  }
}

__global__ __launch_bounds__(THREADS) void scan_fix(int* __restrict__ arr,
                                                    const int* __restrict__ bsums,
                                                    int M, int TOT) {
  int i = blockIdx.x * THREADS + threadIdx.x;
  if (i < M) arr[i] += bsums[i >> 10];
  if (i == 0) arr[M] = TOT;
}

__global__ __launch_bounds__(THREADS) void bucket_scatter(
    const int* __restrict__ src, const int* __restrict__ dst,
    const int* __restrict__ base, int2* __restrict__ buck, int E, int CH, int P) {
  __shared__ int cur[256];
  int b = blockIdx.x, t = threadIdx.x;
  if (t < P) cur[t] = base[t * NB + b];
  __syncthreads();
  int lo = b * CH;
  int hi = min(lo + CH, E);
  for (int i = lo + t; i < hi; i += THREADS) {
    int d = dst[i];
    int pos = atomicAdd(&cur[d >> NPSHIFT], 1);
    buck[pos] = make_int2(src[i], d);
  }
}

__global__ __launch_bounds__(THREADS) void build_csr(
    const int2* __restrict__ buck, const int* __restrict__ base,
    int* __restrict__ rs, int* __restrict__ csr, int N, int E, int P) {
  __shared__ int hA[NPSZ], hB[NPSZ], cur[NPSZ];
  int p = blockIdx.x, t = threadIdx.x;
  hA[t] = 0;
  hA[t + 256] = 0;
  __syncthreads();
  int pstart = base[p * NB];
  int pend = base[(p + 1) * NB];
  for (int i = pstart + t; i < pend; i += THREADS)
    atomicAdd(&hA[buck[i].y & (NPSZ - 1)], 1);
  __syncthreads();
  int* s = hA;
  int* d2 = hB;
  for (int off = 1; off < NPSZ; off <<= 1) {
#pragma unroll
    for (int r = 0; r < 2; ++r) {
      int idx = t + r * 256;
      int v = s[idx];
      if (idx >= off) v += s[idx - off];
      d2[idx] = v;
    }
    __syncthreads();
    int* tmp = s;
    s = d2;
    d2 = tmp;
  }
#pragma unroll
  for (int r = 0; r < 2; ++r) {
    int idx = t + r * 256;
    int excl = idx ? s[idx - 1] : 0;
    cur[idx] = excl;
    int node = (p << NPSHIFT) + idx;
    if (node < N) rs[node] = pstart + excl;
  }
  if (p == P - 1 && t == 0) rs[N] = E;
  __syncthreads();
  for (int i = pstart + t; i < pend; i += THREADS) {
    int2 e = buck[i];
    int pos = atomicAdd(&cur[e.y & (NPSZ - 1)], 1);
    csr[pstart + pos] = e.x;
  }
}

// ---------------- dst-centric aggregation (bf16 gather) ----------------

template <int FINAL>
__global__ __launch_bounds__(THREADS) void agg_kernel(
    const u16* __restrict__ H, const u16* __restrict__ GAMMA,
    const u16* __restrict__ BETA, const float* __restrict__ S,
    const int* __restrict__ rs, const int* __restrict__ csr,
    u16* __restrict__ Xn, const float* __restrict__ Wout,
    const float* __restrict__ bout, float* __restrict__ out, int N) {
  int node = blockIdx.x * 4 + (threadIdx.x >> 6);
  int lane = threadIdx.x & 63;
  if (node >= N) return;
  int beg = rs[node], end = rs[node + 1];
  size_t no = (size_t)node * 64 + lane;
  float g = b2f(GAMMA[no]), b = b2f(BETA[no]);
  float acc = 0.f;
  int i = beg;
  for (; i + 4 <= end; i += 4) {
    int s0 = csr[i], s1 = csr[i + 1], s2 = csr[i + 2], s3 = csr[i + 3];
    float h0 = b2f(H[(size_t)s0 * 64 + lane]);
    float h1 = b2f(H[(size_t)s1 * 64 + lane]);
    float h2 = b2f(H[(size_t)s2 * 64 + lane]);
    float h3 = b2f(H[(size_t)s3 * 64 + lane]);
    acc += fmaxf(fmaf(g, h0, b), 0.f);
    acc += fmaxf(fmaf(g, h1, b), 0.f);
    acc += fmaxf(fmaf(g, h2, b), 0.f);
    acc += fmaxf(fmaf(g, h3, b), 0.f);
  }
  for (; i < end; ++i) {
    float h0 = b2f(H[(size_t)csr[i] * 64 + lane]);
    acc += fmaxf(fmaf(g, h0, b), 0.f);
  }
  float inv = 1.f / fmaxf((float)(end - beg), 1.f);
  float v = fmaf(acc, inv, S[no]);
  v = v > 0.f ? v : 0.01f * v;
  if (FINAL == 0) {
    Xn[no] = f2b(v);
  } else {
    v *= Wout[lane];
#pragma unroll
    for (int off = 32; off; off >>= 1) v += __shfl_xor(v, off, 64);
    if (lane == 0) out[node] = v + bout[0];
  }
}

extern "C" void kernel_launch(void* const* d_in, const int* in_sizes, int n_in,
                              void* d_out, int out_size, void* d_ws, size_t ws_size,
                              hipStream_t stream) {
  const float* x = (const float*)d_in[0];
  const int* ei = (const int*)d_in[1];
  const float* Wlin1 = (const float*)d_in[2];
  const float* Wfilm1 = (const float*)d_in[3];
  const float* bfilm1 = (const float*)d_in[4];
  const float* Wskip1 = (const float*)d_in[5];
  const float* Wfs1 = (const float*)d_in[6];
  const float* Wlin2 = (const float*)d_in[7];
  const float* Wfilm2 = (const float*)d_in[8];
  const float* bfilm2 = (const float*)d_in[9];
  const float* Wskip2 = (const float*)d_in[10];
  const float* Wfs2 = (const float*)d_in[11];
  const float* Wout = (const float*)d_in[12];
  const float* bout = (const float*)d_in[13];

  int N = in_sizes[0] / 64;
  int E = in_sizes[1] / 2;
  const int* src = ei;
  const int* dst = ei + E;

  int P = (N + NPSZ - 1) >> NPSHIFT;
  int CH = (E + NB - 1) / NB;
  int M = P * NB;

  size_t NF = (size_t)N * 64;
  char* p = (char*)d_ws;
  u16* H = (u16*)p;
  p += NF * 2;
  u16* BETA = (u16*)p;
  p += NF * 2;
  u16* GAMMA = (u16*)p;
  p += NF * 2;
  float* S = (float*)p;
  p += NF * 4;
  u16* X2 = (u16*)p;            // aliased with buck (dead before X2 written)
  int2* buck = (int2*)p;
  size_t bsz = (size_t)E * 8, xsz = NF * 2;
  p += (bsz > xsz ? bsz : xsz);
  u16* Wp = (u16*)p;
  p += 12 * 4096 * 2;
  int* rs = (int*)p;
  p += (size_t)(N + 2) * 4;
  int* csr = (int*)p;
  p += (size_t)E * 4;
  int* counts = (int*)p;
  p += (size_t)(M + 2) * 4;
  int* bsums = (int*)p;

  int gemm_blocks = (N + 63) / 64;
  int agg_blocks = (N + 3) / 4;
  int nbM = (M + 1023) / 1024;

  // ---- weight prep ----
  WPack wp;
  wp.m[0] = {Wskip1, 64, 0};
  wp.m[1] = {Wfs1, 128, 0};
  wp.m[2] = {Wfs1, 128, 64};
  wp.m[3] = {Wlin1, 64, 0};
  wp.m[4] = {Wfilm1, 128, 0};
  wp.m[5] = {Wfilm1, 128, 64};
  wp.m[6] = {Wskip2, 64, 0};
  wp.m[7] = {Wfs2, 128, 0};
  wp.m[8] = {Wfs2, 128, 64};
  wp.m[9] = {Wlin2, 64, 0};
  wp.m[10] = {Wfilm2, 128, 0};
  wp.m[11] = {Wfilm2, 128, 64};
  prep_w<<<12, THREADS, 0, stream>>>(wp, Wp);

  // ---- CSR build ----
  hist_part<<<NB, THREADS, 0, stream>>>(dst, counts, E, CH, P);
  scan_block<<<nbM, THREADS, 0, stream>>>(counts, bsums, M);
  scan_tops<<<1, 64, 0, stream>>>(bsums, nbM);
  scan_fix<<<(M + THREADS - 1) / THREADS, THREADS, 0, stream>>>(counts, bsums, M, E);
  bucket_scatter<<<NB, THREADS, 0, stream>>>(src, dst, counts, buck, E, CH, P);
  build_csr<<<P, THREADS, 0, stream>>>(buck, counts, rs, csr, N, E, P);

  // ---- layer 1 ----
  gemm_mfma<0><<<gemm_blocks, THREADS, 0, stream>>>(x, N, Wp, bfilm1, H, BETA, GAMMA, S);
  agg_kernel<0><<<agg_blocks, THREADS, 0, stream>>>(H, GAMMA, BETA, S, rs, csr, X2,
                                                    nullptr, nullptr, nullptr, N);

  // ---- layer 2 ----
  gemm_mfma<1><<<gemm_blocks, THREADS, 0, stream>>>(X2, N, Wp + 6 * 4096, bfilm2, H,
                                                    BETA, GAMMA, S);
  agg_kernel<1><<<agg_blocks, THREADS, 0, stream>>>(H, GAMMA, BETA, S, rs, csr, nullptr,
                                                    Wout, bout, (float*)d_out, N);
}

// Round 6
// 239.199 us; speedup vs baseline: 4.2660x; 1.1134x over previous
//
#include <hip/hip_runtime.h>
#include <cstddef>

// ---------------------------------------------------------------------------
// GraphFiLM: 2x FiLMConv(mean agg) + leaky_relu + linear head.
// Round 5: agg v2 — 2 feats/lane (packed bf16x2 dword gather), 2 edges per
// wave-iteration, 8 edges in flight; u32-packed bucket entries.
// ---------------------------------------------------------------------------

#define THREADS 256
#define NB 256
#define NPSHIFT 9
#define NPSZ 512

typedef unsigned short u16;
typedef unsigned int u32;
typedef short bf16x8 __attribute__((ext_vector_type(8)));
typedef float f32x4 __attribute__((ext_vector_type(4)));

__device__ __forceinline__ u16 f2b(float f) {
  u32 u = __float_as_uint(f);
  u32 r = (u + 0x7FFFu + ((u >> 16) & 1u)) >> 16;
  return (u16)r;
}
__device__ __forceinline__ float b2f(u16 u) {
  return __uint_as_float(((u32)u) << 16);
}

// ---------------- weight prep: W^T, bf16, swizzled ----------------
struct WSrc {
  const float* p;
  int ld;
  int off;
};
struct WPack {
  WSrc m[12];
};

__global__ __launch_bounds__(THREADS) void prep_w(WPack wp, u16* __restrict__ Wp) {
  int b = blockIdx.x, t = threadIdx.x;
  WSrc ws = wp.m[b];
  u16* dst = Wp + b * 4096;
#pragma unroll
  for (int i = 0; i < 16; ++i) {
    int e = t + 256 * i;
    int n = e >> 6, k = e & 63;
    float v = ws.p[(size_t)k * ws.ld + ws.off + n];
    dst[e ^ ((n & 7) << 3)] = f2b(v);
  }
}

// ---------------- fused 6-matmul MFMA GEMM per layer ----------------
template <int INBF16>
__global__ __launch_bounds__(THREADS) void gemm_mfma(
    const void* __restrict__ Xv, int N, const u16* __restrict__ WpL,
    const float* __restrict__ bfilm, u16* __restrict__ H, u16* __restrict__ BETA,
    u16* __restrict__ GAMMA, float* __restrict__ S) {
  __shared__ u16 XT[64 * 64];
  __shared__ u16 WT[6 * 64 * 64];
  int t = threadIdx.x;
  int row0 = blockIdx.x * 64;

  {
    int row = t >> 2, kq = (t & 3) * 16;
    int gr = row0 + row;
    uint4 w0 = {0, 0, 0, 0}, w1 = {0, 0, 0, 0};
    if (gr < N) {
      if (INBF16) {
        const uint4* xp = (const uint4*)((const u16*)Xv + (size_t)gr * 64 + kq);
        w0 = xp[0];
        w1 = xp[1];
      } else {
        const float* xp = (const float*)Xv + (size_t)gr * 64 + kq;
        float4 f0 = ((const float4*)xp)[0];
        float4 f1 = ((const float4*)xp)[1];
        float4 f2 = ((const float4*)xp)[2];
        float4 f3 = ((const float4*)xp)[3];
        w0.x = f2b(f0.x) | ((u32)f2b(f0.y) << 16);
        w0.y = f2b(f0.z) | ((u32)f2b(f0.w) << 16);
        w0.z = f2b(f1.x) | ((u32)f2b(f1.y) << 16);
        w0.w = f2b(f1.z) | ((u32)f2b(f1.w) << 16);
        w1.x = f2b(f2.x) | ((u32)f2b(f2.y) << 16);
        w1.y = f2b(f2.z) | ((u32)f2b(f2.w) << 16);
        w1.z = f2b(f3.x) | ((u32)f2b(f3.y) << 16);
        w1.w = f2b(f3.z) | ((u32)f2b(f3.w) << 16);
      }
    }
    int e = row * 64 + kq;
    int s = (row & 7) << 3;
    *(uint4*)&XT[e ^ s] = w0;
    *(uint4*)&XT[(e + 8) ^ s] = w1;
  }
  {
    const uint4* wsrc = (const uint4*)WpL;
    uint4* wdst = (uint4*)WT;
    for (int i = t; i < 3072; i += THREADS) wdst[i] = wsrc[i];
  }
  __syncthreads();

  int lane = t & 63, wid = t >> 6;
  int arow = wid * 16 + (lane & 15);
  int kb = (lane >> 4) << 3;
  int as = (arow & 7) << 3;
  bf16x8 A0 = *(const bf16x8*)&XT[(arow * 64 + kb) ^ as];
  bf16x8 A1 = *(const bf16x8*)&XT[(arow * 64 + 32 + kb) ^ as];

  auto bfrag = [&](int mat, int ct, int kk) -> bf16x8 {
    int n = ct * 16 + (lane & 15);
    int e = (n * 64 + kk * 32 + kb) ^ ((n & 7) << 3);
    return *(const bf16x8*)&WT[mat * 4096 + e];
  };

  const f32x4 z = {0.f, 0.f, 0.f, 0.f};
  int rbase = wid * 16 + ((lane >> 4) << 2);
  int cbase = lane & 15;

  {
    f32x4 a0[4], a1[4], a2[4];
#pragma unroll
    for (int ct = 0; ct < 4; ++ct) {
      a0[ct] = z;
      a1[ct] = z;
      a2[ct] = z;
    }
#pragma unroll
    for (int ct = 0; ct < 4; ++ct) {
      a0[ct] = __builtin_amdgcn_mfma_f32_16x16x32_bf16(A0, bfrag(0, ct, 0), a0[ct], 0, 0, 0);
      a0[ct] = __builtin_amdgcn_mfma_f32_16x16x32_bf16(A1, bfrag(0, ct, 1), a0[ct], 0, 0, 0);
      a1[ct] = __builtin_amdgcn_mfma_f32_16x16x32_bf16(A0, bfrag(1, ct, 0), a1[ct], 0, 0, 0);
      a1[ct] = __builtin_amdgcn_mfma_f32_16x16x32_bf16(A1, bfrag(1, ct, 1), a1[ct], 0, 0, 0);
      a2[ct] = __builtin_amdgcn_mfma_f32_16x16x32_bf16(A0, bfrag(2, ct, 0), a2[ct], 0, 0, 0);
      a2[ct] = __builtin_amdgcn_mfma_f32_16x16x32_bf16(A1, bfrag(2, ct, 1), a2[ct], 0, 0, 0);
    }
#pragma unroll
    for (int ct = 0; ct < 4; ++ct) {
      int c = ct * 16 + cbase;
#pragma unroll
      for (int r = 0; r < 4; ++r) {
        int gr = row0 + rbase + r;
        if (gr < N) {
          float v = fmaxf(fmaf(a2[ct][r], a0[ct][r], a1[ct][r]), 0.f);
          S[(size_t)gr * 64 + c] = v;
        }
      }
    }
  }

  {
    f32x4 a0[4], a1[4], a2[4];
#pragma unroll
    for (int ct = 0; ct < 4; ++ct) {
      a0[ct] = z;
      a1[ct] = z;
      a2[ct] = z;
    }
#pragma unroll
    for (int ct = 0; ct < 4; ++ct) {
      a0[ct] = __builtin_amdgcn_mfma_f32_16x16x32_bf16(A0, bfrag(3, ct, 0), a0[ct], 0, 0, 0);
      a0[ct] = __builtin_amdgcn_mfma_f32_16x16x32_bf16(A1, bfrag(3, ct, 1), a0[ct], 0, 0, 0);
      a1[ct] = __builtin_amdgcn_mfma_f32_16x16x32_bf16(A0, bfrag(4, ct, 0), a1[ct], 0, 0, 0);
      a1[ct] = __builtin_amdgcn_mfma_f32_16x16x32_bf16(A1, bfrag(4, ct, 1), a1[ct], 0, 0, 0);
      a2[ct] = __builtin_amdgcn_mfma_f32_16x16x32_bf16(A0, bfrag(5, ct, 0), a2[ct], 0, 0, 0);
      a2[ct] = __builtin_amdgcn_mfma_f32_16x16x32_bf16(A1, bfrag(5, ct, 1), a2[ct], 0, 0, 0);
    }
#pragma unroll
    for (int ct = 0; ct < 4; ++ct) {
      int c = ct * 16 + cbase;
      float bb = bfilm[c];
      float bg = bfilm[64 + c];
#pragma unroll
      for (int r = 0; r < 4; ++r) {
        int gr = row0 + rbase + r;
        if (gr < N) {
          size_t o = (size_t)gr * 64 + c;
          H[o] = f2b(a0[ct][r]);
          BETA[o] = f2b(a1[ct][r] + bb);
          GAMMA[o] = f2b(a2[ct][r] + bg);
        }
      }
    }
  }
}

// ---------------- CSR build: bucketed counting sort ----------------

__global__ __launch_bounds__(THREADS) void hist_part(const int* __restrict__ dst,
                                                     int* __restrict__ counts,
                                                     int E, int CH, int P) {
  __shared__ int h[256];
  int b = blockIdx.x, t = threadIdx.x;
  h[t] = 0;
  __syncthreads();
  int lo = b * CH;
  int hi = min(lo + CH, E);
  for (int i = lo + t; i < hi; i += THREADS) atomicAdd(&h[dst[i] >> NPSHIFT], 1);
  __syncthreads();
  if (t < P) counts[t * NB + b] = h[t];
}

__global__ __launch_bounds__(THREADS) void scan_block(int* __restrict__ arr,
                                                      int* __restrict__ bsums, int M) {
  __shared__ int ts[THREADS];
  int t = threadIdx.x;
  int base = blockIdx.x * 1024 + t * 4;
  int v0 = 0, v1 = 0, v2 = 0, v3 = 0;
  if (base + 0 < M) v0 = arr[base + 0];
  if (base + 1 < M) v1 = arr[base + 1];
  if (base + 2 < M) v2 = arr[base + 2];
  if (base + 3 < M) v3 = arr[base + 3];
  int s = v0 + v1 + v2 + v3;
  ts[t] = s;
  __syncthreads();
  for (int off = 1; off < THREADS; off <<= 1) {
    int x = (t >= off) ? ts[t - off] : 0;
    __syncthreads();
    ts[t] += x;
    __syncthreads();
  }
  int eb = ts[t] - s;
  if (base + 0 < M) arr[base + 0] = eb;
  if (base + 1 < M) arr[base + 1] = eb + v0;
  if (base + 2 < M) arr[base + 2] = eb + v0 + v1;
  if (base + 3 < M) arr[base + 3] = eb + v0 + v1 + v2;
  if (t == THREADS - 1) bsums[blockIdx.x] = ts[t];
}

__global__ void scan_tops(int* __restrict__ bsums, int nb) {
  if (threadIdx.x == 0 && blockIdx.x == 0) {
    int run = 0;
    for (int i = 0; i < nb; ++i) {
      int x = bsums[i];
      bsums[i] = run;
      run += x;
    }
  }
}

__global__ __launch_bounds__(THREADS) void scan_fix(int* __restrict__ arr,
                                                    const int* __restrict__ bsums,
                                                    int M, int TOT) {
  int i = blockIdx.x * THREADS + threadIdx.x;
  if (i < M) arr[i] += bsums[i >> 10];
  if (i == 0) arr[M] = TOT;
}

// packed entry: src (17 bits) | dst_lo (9 bits) << 17
__global__ __launch_bounds__(THREADS) void bucket_scatter(
    const int* __restrict__ src, const int* __restrict__ dst,
    const int* __restrict__ base, u32* __restrict__ buck, int E, int CH, int P) {
  __shared__ int cur[256];
  int b = blockIdx.x, t = threadIdx.x;
  if (t < P) cur[t] = base[t * NB + b];
  __syncthreads();
  int lo = b * CH;
  int hi = min(lo + CH, E);
  for (int i = lo + t; i < hi; i += THREADS) {
    int d = dst[i];
    int pos = atomicAdd(&cur[d >> NPSHIFT], 1);
    buck[pos] = (u32)src[i] | ((u32)(d & (NPSZ - 1)) << 17);
  }
}

__global__ __launch_bounds__(THREADS) void build_csr(
    const u32* __restrict__ buck, const int* __restrict__ base,
    int* __restrict__ rs, int* __restrict__ csr, int N, int E, int P) {
  __shared__ int hA[NPSZ], hB[NPSZ], cur[NPSZ];
  int p = blockIdx.x, t = threadIdx.x;
  hA[t] = 0;
  hA[t + 256] = 0;
  __syncthreads();
  int pstart = base[p * NB];
  int pend = base[(p + 1) * NB];
  for (int i = pstart + t; i < pend; i += THREADS)
    atomicAdd(&hA[buck[i] >> 17], 1);
  __syncthreads();
  int* s = hA;
  int* d2 = hB;
  for (int off = 1; off < NPSZ; off <<= 1) {
#pragma unroll
    for (int r = 0; r < 2; ++r) {
      int idx = t + r * 256;
      int v = s[idx];
      if (idx >= off) v += s[idx - off];
      d2[idx] = v;
    }
    __syncthreads();
    int* tmp = s;
    s = d2;
    d2 = tmp;
  }
#pragma unroll
  for (int r = 0; r < 2; ++r) {
    int idx = t + r * 256;
    int excl = idx ? s[idx - 1] : 0;
    cur[idx] = excl;
    int node = (p << NPSHIFT) + idx;
    if (node < N) rs[node] = pstart + excl;
  }
  if (p == P - 1 && t == 0) rs[N] = E;
  __syncthreads();
  for (int i = pstart + t; i < pend; i += THREADS) {
    u32 w = buck[i];
    int pos = atomicAdd(&cur[w >> 17], 1);
    csr[pstart + pos] = (int)(w & 0x1FFFFu);
  }
}

// ---------------- dst-centric aggregation v2 ----------------
// wave = 1 node; lane handles feats {2*fl, 2*fl+1}; halves process
// interleaved edges (8 in flight); halves combined via shfl_xor(32).

template <int FINAL>
__global__ __launch_bounds__(THREADS) void agg_kernel(
    const u16* __restrict__ H, const u16* __restrict__ GAMMA,
    const u16* __restrict__ BETA, const float* __restrict__ S,
    const int* __restrict__ rs, const int* __restrict__ csr,
    u16* __restrict__ Xn, const float* __restrict__ Wout,
    const float* __restrict__ bout, float* __restrict__ out, int N) {
  int node = blockIdx.x * 4 + (threadIdx.x >> 6);
  int lane = threadIdx.x & 63;
  if (node >= N) return;
  int half = lane >> 5;
  int fl = lane & 31;
  int beg = rs[node], end = rs[node + 1];
  size_t nb2 = (size_t)node * 32 + fl;  // dword index into [N][64] bf16
  u32 gp = ((const u32*)GAMMA)[nb2];
  u32 bp = ((const u32*)BETA)[nb2];
  float g0 = b2f((u16)gp), g1 = b2f((u16)(gp >> 16));
  float b0 = b2f((u16)bp), b1 = b2f((u16)(bp >> 16));
  const u32* H32 = (const u32*)H;
  float a0 = 0.f, a1 = 0.f;
  int i = beg + half;
  for (; i + 6 < end; i += 8) {
    int s0 = csr[i], s1 = csr[i + 2], s2 = csr[i + 4], s3 = csr[i + 6];
    u32 h0 = H32[(size_t)s0 * 32 + fl];
    u32 h1 = H32[(size_t)s1 * 32 + fl];
    u32 h2 = H32[(size_t)s2 * 32 + fl];
    u32 h3 = H32[(size_t)s3 * 32 + fl];
    a0 += fmaxf(fmaf(g0, b2f((u16)h0), b0), 0.f);
    a1 += fmaxf(fmaf(g1, b2f((u16)(h0 >> 16)), b1), 0.f);
    a0 += fmaxf(fmaf(g0, b2f((u16)h1), b0), 0.f);
    a1 += fmaxf(fmaf(g1, b2f((u16)(h1 >> 16)), b1), 0.f);
    a0 += fmaxf(fmaf(g0, b2f((u16)h2), b0), 0.f);
    a1 += fmaxf(fmaf(g1, b2f((u16)(h2 >> 16)), b1), 0.f);
    a0 += fmaxf(fmaf(g0, b2f((u16)h3), b0), 0.f);
    a1 += fmaxf(fmaf(g1, b2f((u16)(h3 >> 16)), b1), 0.f);
  }
  for (; i < end; i += 2) {
    u32 h0 = H32[(size_t)csr[i] * 32 + fl];
    a0 += fmaxf(fmaf(g0, b2f((u16)h0), b0), 0.f);
    a1 += fmaxf(fmaf(g1, b2f((u16)(h0 >> 16)), b1), 0.f);
  }
  // combine the two interleaved halves
  a0 += __shfl_xor(a0, 32, 64);
  a1 += __shfl_xor(a1, 32, 64);
  float inv = 1.f / fmaxf((float)(end - beg), 1.f);
  float2 sv = ((const float2*)S)[nb2];
  float v0 = fmaf(a0, inv, sv.x);
  float v1 = fmaf(a1, inv, sv.y);
  v0 = v0 > 0.f ? v0 : 0.01f * v0;
  v1 = v1 > 0.f ? v1 : 0.01f * v1;
  if (FINAL == 0) {
    if (half == 0) {
      u32 pw = (u32)f2b(v0) | ((u32)f2b(v1) << 16);
      ((u32*)Xn)[nb2] = pw;
    }
  } else {
    float2 w2 = ((const float2*)Wout)[fl];
    float v = fmaf(v0, w2.x, v1 * w2.y);
#pragma unroll
    for (int off = 16; off; off >>= 1) v += __shfl_xor(v, off, 64);
    if (lane == 0) out[node] = v + bout[0];
  }
}

extern "C" void kernel_launch(void* const* d_in, const int* in_sizes, int n_in,
                              void* d_out, int out_size, void* d_ws, size_t ws_size,
                              hipStream_t stream) {
  const float* x = (const float*)d_in[0];
  const int* ei = (const int*)d_in[1];
  const float* Wlin1 = (const float*)d_in[2];
  const float* Wfilm1 = (const float*)d_in[3];
  const float* bfilm1 = (const float*)d_in[4];
  const float* Wskip1 = (const float*)d_in[5];
  const float* Wfs1 = (const float*)d_in[6];
  const float* Wlin2 = (const float*)d_in[7];
  const float* Wfilm2 = (const float*)d_in[8];
  const float* bfilm2 = (const float*)d_in[9];
  const float* Wskip2 = (const float*)d_in[10];
  const float* Wfs2 = (const float*)d_in[11];
  const float* Wout = (const float*)d_in[12];
  const float* bout = (const float*)d_in[13];

  int N = in_sizes[0] / 64;
  int E = in_sizes[1] / 2;
  const int* src = ei;
  const int* dst = ei + E;

  int P = (N + NPSZ - 1) >> NPSHIFT;
  int CH = (E + NB - 1) / NB;
  int M = P * NB;

  size_t NF = (size_t)N * 64;
  char* p = (char*)d_ws;
  u16* H = (u16*)p;
  p += NF * 2;
  u16* BETA = (u16*)p;
  p += NF * 2;
  u16* GAMMA = (u16*)p;
  p += NF * 2;
  float* S = (float*)p;
  p += NF * 4;
  u16* X2 = (u16*)p;  // aliased with buck (buck dead before X2 written)
  u32* buck = (u32*)p;
  size_t bsz = (size_t)E * 4, xsz = NF * 2;
  p += (bsz > xsz ? bsz : xsz);
  u16* Wp = (u16*)p;
  p += 12 * 4096 * 2;
  int* rs = (int*)p;
  p += (size_t)(N + 2) * 4;
  int* csr = (int*)p;
  p += (size_t)E * 4;
  int* counts = (int*)p;
  p += (size_t)(M + 2) * 4;
  int* bsums = (int*)p;

  int gemm_blocks = (N + 63) / 64;
  int agg_blocks = (N + 3) / 4;
  int nbM = (M + 1023) / 1024;

  WPack wp;
  wp.m[0] = {Wskip1, 64, 0};
  wp.m[1] = {Wfs1, 128, 0};
  wp.m[2] = {Wfs1, 128, 64};
  wp.m[3] = {Wlin1, 64, 0};
  wp.m[4] = {Wfilm1, 128, 0};
  wp.m[5] = {Wfilm1, 128, 64};
  wp.m[6] = {Wskip2, 64, 0};
  wp.m[7] = {Wfs2, 128, 0};
  wp.m[8] = {Wfs2, 128, 64};
  wp.m[9] = {Wlin2, 64, 0};
  wp.m[10] = {Wfilm2, 128, 0};
  wp.m[11] = {Wfilm2, 128, 64};
  prep_w<<<12, THREADS, 0, stream>>>(wp, Wp);

  hist_part<<<NB, THREADS, 0, stream>>>(dst, counts, E, CH, P);
  scan_block<<<nbM, THREADS, 0, stream>>>(counts, bsums, M);
  scan_tops<<<1, 64, 0, stream>>>(bsums, nbM);
  scan_fix<<<(M + THREADS - 1) / THREADS, THREADS, 0, stream>>>(counts, bsums, M, E);
  bucket_scatter<<<NB, THREADS, 0, stream>>>(src, dst, counts, buck, E, CH, P);
  build_csr<<<P, THREADS, 0, stream>>>(buck, counts, rs, csr, N, E, P);

  gemm_mfma<0><<<gemm_blocks, THREADS, 0, stream>>>(x, N, Wp, bfilm1, H, BETA, GAMMA, S);
  agg_kernel<0><<<agg_blocks, THREADS, 0, stream>>>(H, GAMMA, BETA, S, rs, csr, X2,
                                                    nullptr, nullptr, nullptr, N);

  gemm_mfma<1><<<gemm_blocks, THREADS, 0, stream>>>(X2, N, Wp + 6 * 4096, bfilm2, H,
                                                    BETA, GAMMA, S);
  agg_kernel<1><<<agg_blocks, THREADS, 0, stream>>>(H, GAMMA, BETA, S, rs, csr, nullptr,
                                                    Wout, bout, (float*)d_out, N);
}

// Round 8
// 229.028 us; speedup vs baseline: 4.4555x; 1.0444x over previous
//
#include <hip/hip_runtime.h>
#include <cstddef>

// ---------------------------------------------------------------------------
// GraphFiLM: 2x FiLMConv(mean agg) + leaky_relu + linear head.
// Round 7: agg v3b — shfl-broadcast CSR indices, but ALL shfls in uniform
// control flow (R6's divergent-tail bpermute read inactive lanes -> garbage).
// Tail accumulation predicated with selects, not branches.
// ---------------------------------------------------------------------------

#define THREADS 256
#define NB 256
#define NPSHIFT 9
#define NPSZ 512

typedef unsigned short u16;
typedef unsigned int u32;
typedef short bf16x8 __attribute__((ext_vector_type(8)));
typedef float f32x4 __attribute__((ext_vector_type(4)));

__device__ __forceinline__ u16 f2b(float f) {
  u32 u = __float_as_uint(f);
  u32 r = (u + 0x7FFFu + ((u >> 16) & 1u)) >> 16;
  return (u16)r;
}
__device__ __forceinline__ float b2f(u16 u) {
  return __uint_as_float(((u32)u) << 16);
}

// ---------------- weight prep: W^T, bf16, swizzled ----------------
struct WSrc {
  const float* p;
  int ld;
  int off;
};
struct WPack {
  WSrc m[12];
};

__global__ __launch_bounds__(THREADS) void prep_w(WPack wp, u16* __restrict__ Wp) {
  int b = blockIdx.x, t = threadIdx.x;
  WSrc ws = wp.m[b];
  u16* dst = Wp + b * 4096;
#pragma unroll
  for (int i = 0; i < 16; ++i) {
    int e = t + 256 * i;
    int n = e >> 6, k = e & 63;
    float v = ws.p[(size_t)k * ws.ld + ws.off + n];
    dst[e ^ ((n & 7) << 3)] = f2b(v);
  }
}

// ---------------- fused 6-matmul MFMA GEMM per layer ----------------
template <int INBF16>
__global__ __launch_bounds__(THREADS) void gemm_mfma(
    const void* __restrict__ Xv, int N, const u16* __restrict__ WpL,
    const float* __restrict__ bfilm, u16* __restrict__ H, u16* __restrict__ BETA,
    u16* __restrict__ GAMMA, float* __restrict__ S) {
  __shared__ u16 XT[64 * 64];
  __shared__ u16 WT[6 * 64 * 64];
  int t = threadIdx.x;
  int row0 = blockIdx.x * 64;

  {
    int row = t >> 2, kq = (t & 3) * 16;
    int gr = row0 + row;
    uint4 w0 = {0, 0, 0, 0}, w1 = {0, 0, 0, 0};
    if (gr < N) {
      if (INBF16) {
        const uint4* xp = (const uint4*)((const u16*)Xv + (size_t)gr * 64 + kq);
        w0 = xp[0];
        w1 = xp[1];
      } else {
        const float* xp = (const float*)Xv + (size_t)gr * 64 + kq;
        float4 f0 = ((const float4*)xp)[0];
        float4 f1 = ((const float4*)xp)[1];
        float4 f2 = ((const float4*)xp)[2];
        float4 f3 = ((const float4*)xp)[3];
        w0.x = f2b(f0.x) | ((u32)f2b(f0.y) << 16);
        w0.y = f2b(f0.z) | ((u32)f2b(f0.w) << 16);
        w0.z = f2b(f1.x) | ((u32)f2b(f1.y) << 16);
        w0.w = f2b(f1.z) | ((u32)f2b(f1.w) << 16);
        w1.x = f2b(f2.x) | ((u32)f2b(f2.y) << 16);
        w1.y = f2b(f2.z) | ((u32)f2b(f2.w) << 16);
        w1.z = f2b(f3.x) | ((u32)f2b(f3.y) << 16);
        w1.w = f2b(f3.z) | ((u32)f2b(f3.w) << 16);
      }
    }
    int e = row * 64 + kq;
    int s = (row & 7) << 3;
    *(uint4*)&XT[e ^ s] = w0;
    *(uint4*)&XT[(e + 8) ^ s] = w1;
  }
  {
    const uint4* wsrc = (const uint4*)WpL;
    uint4* wdst = (uint4*)WT;
    for (int i = t; i < 3072; i += THREADS) wdst[i] = wsrc[i];
  }
  __syncthreads();

  int lane = t & 63, wid = t >> 6;
  int arow = wid * 16 + (lane & 15);
  int kb = (lane >> 4) << 3;
  int as = (arow & 7) << 3;
  bf16x8 A0 = *(const bf16x8*)&XT[(arow * 64 + kb) ^ as];
  bf16x8 A1 = *(const bf16x8*)&XT[(arow * 64 + 32 + kb) ^ as];

  auto bfrag = [&](int mat, int ct, int kk) -> bf16x8 {
    int n = ct * 16 + (lane & 15);
    int e = (n * 64 + kk * 32 + kb) ^ ((n & 7) << 3);
    return *(const bf16x8*)&WT[mat * 4096 + e];
  };

  const f32x4 z = {0.f, 0.f, 0.f, 0.f};
  int rbase = wid * 16 + ((lane >> 4) << 2);
  int cbase = lane & 15;

  {
    f32x4 a0[4], a1[4], a2[4];
#pragma unroll
    for (int ct = 0; ct < 4; ++ct) {
      a0[ct] = z;
      a1[ct] = z;
      a2[ct] = z;
    }
#pragma unroll
    for (int ct = 0; ct < 4; ++ct) {
      a0[ct] = __builtin_amdgcn_mfma_f32_16x16x32_bf16(A0, bfrag(0, ct, 0), a0[ct], 0, 0, 0);
      a0[ct] = __builtin_amdgcn_mfma_f32_16x16x32_bf16(A1, bfrag(0, ct, 1), a0[ct], 0, 0, 0);
      a1[ct] = __builtin_amdgcn_mfma_f32_16x16x32_bf16(A0, bfrag(1, ct, 0), a1[ct], 0, 0, 0);
      a1[ct] = __builtin_amdgcn_mfma_f32_16x16x32_bf16(A1, bfrag(1, ct, 1), a1[ct], 0, 0, 0);
      a2[ct] = __builtin_amdgcn_mfma_f32_16x16x32_bf16(A0, bfrag(2, ct, 0), a2[ct], 0, 0, 0);
      a2[ct] = __builtin_amdgcn_mfma_f32_16x16x32_bf16(A1, bfrag(2, ct, 1), a2[ct], 0, 0, 0);
    }
#pragma unroll
    for (int ct = 0; ct < 4; ++ct) {
      int c = ct * 16 + cbase;
#pragma unroll
      for (int r = 0; r < 4; ++r) {
        int gr = row0 + rbase + r;
        if (gr < N) {
          float v = fmaxf(fmaf(a2[ct][r], a0[ct][r], a1[ct][r]), 0.f);
          S[(size_t)gr * 64 + c] = v;
        }
      }
    }
  }

  {
    f32x4 a0[4], a1[4], a2[4];
#pragma unroll
    for (int ct = 0; ct < 4; ++ct) {
      a0[ct] = z;
      a1[ct] = z;
      a2[ct] = z;
    }
#pragma unroll
    for (int ct = 0; ct < 4; ++ct) {
      a0[ct] = __builtin_amdgcn_mfma_f32_16x16x32_bf16(A0, bfrag(3, ct, 0), a0[ct], 0, 0, 0);
      a0[ct] = __builtin_amdgcn_mfma_f32_16x16x32_bf16(A1, bfrag(3, ct, 1), a0[ct], 0, 0, 0);
      a1[ct] = __builtin_amdgcn_mfma_f32_16x16x32_bf16(A0, bfrag(4, ct, 0), a1[ct], 0, 0, 0);
      a1[ct] = __builtin_amdgcn_mfma_f32_16x16x32_bf16(A1, bfrag(4, ct, 1), a1[ct], 0, 0, 0);
      a2[ct] = __builtin_amdgcn_mfma_f32_16x16x32_bf16(A0, bfrag(5, ct, 0), a2[ct], 0, 0, 0);
      a2[ct] = __builtin_amdgcn_mfma_f32_16x16x32_bf16(A1, bfrag(5, ct, 1), a2[ct], 0, 0, 0);
    }
#pragma unroll
    for (int ct = 0; ct < 4; ++ct) {
      int c = ct * 16 + cbase;
      float bb = bfilm[c];
      float bg = bfilm[64 + c];
#pragma unroll
      for (int r = 0; r < 4; ++r) {
        int gr = row0 + rbase + r;
        if (gr < N) {
          size_t o = (size_t)gr * 64 + c;
          H[o] = f2b(a0[ct][r]);
          BETA[o] = f2b(a1[ct][r] + bb);
          GAMMA[o] = f2b(a2[ct][r] + bg);
        }
      }
    }
  }
}

// ---------------- CSR build: bucketed counting sort ----------------

__global__ __launch_bounds__(THREADS) void hist_part(const int* __restrict__ dst,
                                                     int* __restrict__ counts,
                                                     int E, int CH, int P) {
  __shared__ int h[256];
  int b = blockIdx.x, t = threadIdx.x;
  h[t] = 0;
  __syncthreads();
  int lo = b * CH;
  int hi = min(lo + CH, E);
  for (int i = lo + t; i < hi; i += THREADS) atomicAdd(&h[dst[i] >> NPSHIFT], 1);
  __syncthreads();
  if (t < P) counts[t * NB + b] = h[t];
}

__global__ __launch_bounds__(THREADS) void scan_block(int* __restrict__ arr,
                                                      int* __restrict__ bsums, int M) {
  __shared__ int ts[THREADS];
  int t = threadIdx.x;
  int base = blockIdx.x * 1024 + t * 4;
  int v0 = 0, v1 = 0, v2 = 0, v3 = 0;
  if (base + 0 < M) v0 = arr[base + 0];
  if (base + 1 < M) v1 = arr[base + 1];
  if (base + 2 < M) v2 = arr[base + 2];
  if (base + 3 < M) v3 = arr[base + 3];
  int s = v0 + v1 + v2 + v3;
  ts[t] = s;
  __syncthreads();
  for (int off = 1; off < THREADS; off <<= 1) {
    int x = (t >= off) ? ts[t - off] : 0;
    __syncthreads();
    ts[t] += x;
    __syncthreads();
  }
  int eb = ts[t] - s;
  if (base + 0 < M) arr[base + 0] = eb;
  if (base + 1 < M) arr[base + 1] = eb + v0;
  if (base + 2 < M) arr[base + 2] = eb + v0 + v1;
  if (base + 3 < M) arr[base + 3] = eb + v0 + v1 + v2;
  if (t == THREADS - 1) bsums[blockIdx.x] = ts[t];
}

__global__ void scan_tops(int* __restrict__ bsums, int nb) {
  if (threadIdx.x == 0 && blockIdx.x == 0) {
    int run = 0;
    for (int i = 0; i < nb; ++i) {
      int x = bsums[i];
      bsums[i] = run;
      run += x;
    }
  }
}

__global__ __launch_bounds__(THREADS) void scan_fix(int* __restrict__ arr,
                                                    const int* __restrict__ bsums,
                                                    int M, int TOT) {
  int i = blockIdx.x * THREADS + threadIdx.x;
  if (i < M) arr[i] += bsums[i >> 10];
  if (i == 0) arr[M] = TOT;
}

// packed entry: src (17 bits) | dst_lo (9 bits) << 17
__global__ __launch_bounds__(THREADS) void bucket_scatter(
    const int* __restrict__ src, const int* __restrict__ dst,
    const int* __restrict__ base, u32* __restrict__ buck, int E, int CH, int P) {
  __shared__ int cur[256];
  int b = blockIdx.x, t = threadIdx.x;
  if (t < P) cur[t] = base[t * NB + b];
  __syncthreads();
  int lo = b * CH;
  int hi = min(lo + CH, E);
  for (int i = lo + t; i < hi; i += THREADS) {
    int d = dst[i];
    int pos = atomicAdd(&cur[d >> NPSHIFT], 1);
    buck[pos] = (u32)src[i] | ((u32)(d & (NPSZ - 1)) << 17);
  }
}

__global__ __launch_bounds__(THREADS) void build_csr(
    const u32* __restrict__ buck, const int* __restrict__ base,
    int* __restrict__ rs, int* __restrict__ csr, int N, int E, int P) {
  __shared__ int hA[NPSZ], hB[NPSZ], cur[NPSZ];
  int p = blockIdx.x, t = threadIdx.x;
  hA[t] = 0;
  hA[t + 256] = 0;
  __syncthreads();
  int pstart = base[p * NB];
  int pend = base[(p + 1) * NB];
  for (int i = pstart + t; i < pend; i += THREADS)
    atomicAdd(&hA[buck[i] >> 17], 1);
  __syncthreads();
  int* s = hA;
  int* d2 = hB;
  for (int off = 1; off < NPSZ; off <<= 1) {
#pragma unroll
    for (int r = 0; r < 2; ++r) {
      int idx = t + r * 256;
      int v = s[idx];
      if (idx >= off) v += s[idx - off];
      d2[idx] = v;
    }
    __syncthreads();
    int* tmp = s;
    s = d2;
    d2 = tmp;
  }
#pragma unroll
  for (int r = 0; r < 2; ++r) {
    int idx = t + r * 256;
    int excl = idx ? s[idx - 1] : 0;
    cur[idx] = excl;
    int node = (p << NPSHIFT) + idx;
    if (node < N) rs[node] = pstart + excl;
  }
  if (p == P - 1 && t == 0) rs[N] = E;
  __syncthreads();
  for (int i = pstart + t; i < pend; i += THREADS) {
    u32 w = buck[i];
    int pos = atomicAdd(&cur[w >> 17], 1);
    csr[pstart + pos] = (int)(w & 0x1FFFFu);
  }
}

// ---------------- dst-centric aggregation v3b (uniform shfl) ----------------
// wave = 1 node; lane -> feats {2*fl, 2*fl+1}; CSR indices loaded once per
// 64-edge chunk (coalesced), broadcast via shfl executed in UNIFORM control
// flow; halves process interleaved edges; tail predicated with selects.

template <int FINAL>
__global__ __launch_bounds__(THREADS) void agg_kernel(
    const u16* __restrict__ H, const u16* __restrict__ GAMMA,
    const u16* __restrict__ BETA, const float* __restrict__ S,
    const int* __restrict__ rs, const int* __restrict__ csr,
    u16* __restrict__ Xn, const float* __restrict__ Wout,
    const float* __restrict__ bout, float* __restrict__ out, int N, int E) {
  int node = blockIdx.x * 4 + (threadIdx.x >> 6);
  int lane = threadIdx.x & 63;
  if (node >= N) return;
  int half = lane >> 5;
  int fl = lane & 31;
  int beg = rs[node], end = rs[node + 1];
  int deg = end - beg;
  size_t nb2 = (size_t)node * 32 + fl;
  u32 gp = ((const u32*)GAMMA)[nb2];
  u32 bp = ((const u32*)BETA)[nb2];
  float g0 = b2f((u16)gp), g1 = b2f((u16)(gp >> 16));
  float b0 = b2f((u16)bp), b1 = b2f((u16)(bp >> 16));
  const u32* H32 = (const u32*)H;
  float a0 = 0.f, a1 = 0.f;

  for (int c = 0; c < deg; c += 64) {          // uniform trip count
    int nrem = min(deg - c, 64);               // uniform
    int li = beg + c + lane;
    int idxv = csr[li < E ? li : E - 1];       // clamped -> always valid id
    int jj = 0;
    // main: full groups of 8 (uniform condition; both halves same trips)
    for (; jj + 8 <= nrem; jj += 8) {
      int jb = jj + half;
      int s0 = __shfl(idxv, jb, 64);
      int s1 = __shfl(idxv, jb + 2, 64);
      int s2 = __shfl(idxv, jb + 4, 64);
      int s3 = __shfl(idxv, jb + 6, 64);
      u32 h0 = H32[s0 * 32 + fl];
      u32 h1 = H32[s1 * 32 + fl];
      u32 h2 = H32[s2 * 32 + fl];
      u32 h3 = H32[s3 * 32 + fl];
      a0 += fmaxf(fmaf(g0, b2f((u16)h0), b0), 0.f);
      a1 += fmaxf(fmaf(g1, b2f((u16)(h0 >> 16)), b1), 0.f);
      a0 += fmaxf(fmaf(g0, b2f((u16)h1), b0), 0.f);
      a1 += fmaxf(fmaf(g1, b2f((u16)(h1 >> 16)), b1), 0.f);
      a0 += fmaxf(fmaf(g0, b2f((u16)h2), b0), 0.f);
      a1 += fmaxf(fmaf(g1, b2f((u16)(h2 >> 16)), b1), 0.f);
      a0 += fmaxf(fmaf(g0, b2f((u16)h3), b0), 0.f);
      a1 += fmaxf(fmaf(g1, b2f((u16)(h3 >> 16)), b1), 0.f);
    }
    // tail: uniform loop; shfl+gather always execute; adds predicated
    for (; jj < nrem; jj += 2) {
      int jb = jj + half;                      // may equal nrem for one half
      int s0 = __shfl(idxv, jb & 63, 64);      // uniform exec
      u32 h0 = H32[s0 * 32 + fl];              // valid address regardless
      float m0 = fmaxf(fmaf(g0, b2f((u16)h0), b0), 0.f);
      float m1 = fmaxf(fmaf(g1, b2f((u16)(h0 >> 16)), b1), 0.f);
      bool ok = jb < nrem;
      a0 += ok ? m0 : 0.f;
      a1 += ok ? m1 : 0.f;
    }
  }

  a0 += __shfl_xor(a0, 32, 64);
  a1 += __shfl_xor(a1, 32, 64);
  float inv = 1.f / fmaxf((float)deg, 1.f);
  float2 sv = ((const float2*)S)[nb2];
  float v0 = fmaf(a0, inv, sv.x);
  float v1 = fmaf(a1, inv, sv.y);
  v0 = v0 > 0.f ? v0 : 0.01f * v0;
  v1 = v1 > 0.f ? v1 : 0.01f * v1;
  if (FINAL == 0) {
    if (half == 0) {
      u32 pw = (u32)f2b(v0) | ((u32)f2b(v1) << 16);
      ((u32*)Xn)[nb2] = pw;
    }
  } else {
    float2 w2 = ((const float2*)Wout)[fl];
    float v = fmaf(v0, w2.x, v1 * w2.y);
#pragma unroll
    for (int off = 16; off; off >>= 1) v += __shfl_xor(v, off, 64);
    if (lane == 0) out[node] = v + bout[0];
  }
}

extern "C" void kernel_launch(void* const* d_in, const int* in_sizes, int n_in,
                              void* d_out, int out_size, void* d_ws, size_t ws_size,
                              hipStream_t stream) {
  const float* x = (const float*)d_in[0];
  const int* ei = (const int*)d_in[1];
  const float* Wlin1 = (const float*)d_in[2];
  const float* Wfilm1 = (const float*)d_in[3];
  const float* bfilm1 = (const float*)d_in[4];
  const float* Wskip1 = (const float*)d_in[5];
  const float* Wfs1 = (const float*)d_in[6];
  const float* Wlin2 = (const float*)d_in[7];
  const float* Wfilm2 = (const float*)d_in[8];
  const float* bfilm2 = (const float*)d_in[9];
  const float* Wskip2 = (const float*)d_in[10];
  const float* Wfs2 = (const float*)d_in[11];
  const float* Wout = (const float*)d_in[12];
  const float* bout = (const float*)d_in[13];

  int N = in_sizes[0] / 64;
  int E = in_sizes[1] / 2;
  const int* src = ei;
  const int* dst = ei + E;

  int P = (N + NPSZ - 1) >> NPSHIFT;
  int CH = (E + NB - 1) / NB;
  int M = P * NB;

  size_t NF = (size_t)N * 64;
  char* p = (char*)d_ws;
  u16* H = (u16*)p;
  p += NF * 2;
  u16* BETA = (u16*)p;
  p += NF * 2;
  u16* GAMMA = (u16*)p;
  p += NF * 2;
  float* S = (float*)p;
  p += NF * 4;
  u16* X2 = (u16*)p;  // aliased with buck (buck dead before X2 written)
  u32* buck = (u32*)p;
  size_t bsz = (size_t)E * 4, xsz = NF * 2;
  p += (bsz > xsz ? bsz : xsz);
  u16* Wp = (u16*)p;
  p += 12 * 4096 * 2;
  int* rs = (int*)p;
  p += (size_t)(N + 2) * 4;
  int* csr = (int*)p;
  p += (size_t)E * 4;
  int* counts = (int*)p;
  p += (size_t)(M + 2) * 4;
  int* bsums = (int*)p;

  int gemm_blocks = (N + 63) / 64;
  int agg_blocks = (N + 3) / 4;
  int nbM = (M + 1023) / 1024;

  WPack wp;
  wp.m[0] = {Wskip1, 64, 0};
  wp.m[1] = {Wfs1, 128, 0};
  wp.m[2] = {Wfs1, 128, 64};
  wp.m[3] = {Wlin1, 64, 0};
  wp.m[4] = {Wfilm1, 128, 0};
  wp.m[5] = {Wfilm1, 128, 64};
  wp.m[6] = {Wskip2, 64, 0};
  wp.m[7] = {Wfs2, 128, 0};
  wp.m[8] = {Wfs2, 128, 64};
  wp.m[9] = {Wlin2, 64, 0};
  wp.m[10] = {Wfilm2, 128, 0};
  wp.m[11] = {Wfilm2, 128, 64};
  prep_w<<<12, THREADS, 0, stream>>>(wp, Wp);

  hist_part<<<NB, THREADS, 0, stream>>>(dst, counts, E, CH, P);
  scan_block<<<nbM, THREADS, 0, stream>>>(counts, bsums, M);
  scan_tops<<<1, 64, 0, stream>>>(bsums, nbM);
  scan_fix<<<(M + THREADS - 1) / THREADS, THREADS, 0, stream>>>(counts, bsums, M, E);
  bucket_scatter<<<NB, THREADS, 0, stream>>>(src, dst, counts, buck, E, CH, P);
  build_csr<<<P, THREADS, 0, stream>>>(buck, counts, rs, csr, N, E, P);

  gemm_mfma<0><<<gemm_blocks, THREADS, 0, stream>>>(x, N, Wp, bfilm1, H, BETA, GAMMA, S);
  agg_kernel<0><<<agg_blocks, THREADS, 0, stream>>>(H, GAMMA, BETA, S, rs, csr, X2,
                                                    nullptr, nullptr, nullptr, N, E);

  gemm_mfma<1><<<gemm_blocks, THREADS, 0, stream>>>(X2, N, Wp + 6 * 4096, bfilm2, H,
                                                    BETA, GAMMA, S);
  agg_kernel<1><<<agg_blocks, THREADS, 0, stream>>>(H, GAMMA, BETA, S, rs, csr, nullptr,
                                                    Wout, bout, (float*)d_out, N, E);
}